// Round 3
// baseline (189.857 us; speedup 1.0000x reference)
//
#include <hip/hip_runtime.h>
#include <math.h>

#define D 128
#define TWO_D 256
#define S_NEIGH 25
#define NPB 32          // nodes per block in k_main
#define HPAD 260        // padded h row (float4-aligned, breaks pow2 stride)

static constexpr float BN_EPS_C = 1e-5f;
static constexpr float NORM_EPS_C = 1e-6f;

// ---------------- K0: transpose W [128][256] -> Wt [256][128]; zero stats ----------------
__global__ void k_prep(const float* __restrict__ W,
                       float* __restrict__ Wt,
                       float* __restrict__ stats) {
    const int k = blockIdx.x;    // 0..255
    const int j = threadIdx.x;   // 0..127
    Wt[k * D + j] = W[j * TWO_D + k];
    if (k < 2) stats[k * D + j] = 0.0f;
}

// ---------------- K1: gather + mean-agg + linear + relu + column stats ----------------
// 512 threads, 32 nodes/block. LDS 36.6KB -> 4 blocks/CU -> 32 waves/CU (100% occ @ VGPR<=64)
__global__ __launch_bounds__(512, 8) void k_main(
    const float* __restrict__ feat,
    const int* __restrict__ self_idx,
    const int* __restrict__ neigh_idx,
    const float* __restrict__ Wt,
    const float* __restrict__ bias,
    float* __restrict__ out1,     // [N][128] pre-norm output (uses d_out)
    float* __restrict__ stats,    // [0..127]=sum, [128..255]=sumsq
    int N)
{
    __shared__ float h[NPB][HPAD];            // 33280 B; reused for stats partials later
    __shared__ int   s_nidx[NPB * S_NEIGH];   // 800 ints
    __shared__ int   s_sidx[NPB];

    const int t = threadIdx.x;
    const int base = blockIdx.x * NPB;
    const int nvalid = min(NPB, N - base);

    // ---- stage indices into LDS: one coalesced sweep ----
    {
        const int V = nvalid * S_NEIGH;
        const long goff = (long)base * S_NEIGH;
        if (t < (NPB * S_NEIGH) / 4) {              // 200 int4 loaders
            const int e0 = 4 * t;
            if (e0 + 3 < V) {
                ((int4*)s_nidx)[t] = ((const int4*)(neigh_idx + goff))[t];
            } else {
                #pragma unroll
                for (int e = 0; e < 4; ++e)
                    if (e0 + e < V) s_nidx[e0 + e] = neigh_idx[goff + e0 + e];
            }
        } else if (t < (NPB * S_NEIGH) / 4 + NPB) {
            const int i = t - (NPB * S_NEIGH) / 4;
            if (i < nvalid) s_sidx[i] = self_idx[base + i];
        }
    }
    __syncthreads();

    // ---- gather: each half-wave (32 lanes x float4) owns 2 nodes; batched loads (8-9 in flight) ----
    const int hw = t >> 5;        // 0..15
    const int l32 = t & 31;
    const int col = 4 * l32;
    const float* fcol = feat + col;
    #pragma unroll
    for (int p = 0; p < 2; ++p) {
        const int n = hw * 2 + p;
        if (n < nvalid) {
            const int* nid = s_nidx + n * S_NEIGH;
            float4 buf[8];
            float4 sf = *(const float4*)(fcol + (long)s_sidx[n] * D);
            float4 acc = make_float4(0.f, 0.f, 0.f, 0.f);
            #pragma unroll
            for (int b = 0; b < 3; ++b) {
                #pragma unroll
                for (int u = 0; u < 8; ++u)
                    buf[u] = *(const float4*)(fcol + (long)nid[b * 8 + u] * D);
                #pragma unroll
                for (int u = 0; u < 8; ++u) {
                    acc.x += buf[u].x; acc.y += buf[u].y;
                    acc.z += buf[u].z; acc.w += buf[u].w;
                }
            }
            const float4 f24 = *(const float4*)(fcol + (long)nid[24] * D);
            acc.x += f24.x; acc.y += f24.y; acc.z += f24.z; acc.w += f24.w;
            const float r = 1.0f / S_NEIGH;
            acc.x *= r; acc.y *= r; acc.z *= r; acc.w *= r;
            *(float4*)&h[n][col]     = sf;    // h[0:128] = self
            *(float4*)&h[n][D + col] = acc;   // h[128:256] = mean-agg
        }
    }
    __syncthreads();

    // ---- GEMM: out[n][j] = relu(b[j] + sum_k h[n][k]*Wt[k][j]) ----
    // thread: cg = l32 -> cols 4cg..4cg+3 ; slot = hw -> nodes slot*2, slot*2+1
    const float4 b4 = *(const float4*)(bias + col);
    float acc2[2][4];
    #pragma unroll
    for (int p = 0; p < 2; ++p) {
        acc2[p][0] = b4.x; acc2[p][1] = b4.y; acc2[p][2] = b4.z; acc2[p][3] = b4.w;
    }

    for (int k = 0; k < TWO_D; k += 4) {
        const float4 w0 = *(const float4*)(Wt + (long)(k + 0) * D + col);
        const float4 w1 = *(const float4*)(Wt + (long)(k + 1) * D + col);
        const float4 w2 = *(const float4*)(Wt + (long)(k + 2) * D + col);
        const float4 w3 = *(const float4*)(Wt + (long)(k + 3) * D + col);
        #pragma unroll
        for (int p = 0; p < 2; ++p) {
            const float4 hv = *(const float4*)&h[hw * 2 + p][k];
            acc2[p][0] += hv.x * w0.x + hv.y * w1.x + hv.z * w2.x + hv.w * w3.x;
            acc2[p][1] += hv.x * w0.y + hv.y * w1.y + hv.z * w2.y + hv.w * w3.y;
            acc2[p][2] += hv.x * w0.z + hv.y * w1.z + hv.z * w2.z + hv.w * w3.z;
            acc2[p][3] += hv.x * w0.w + hv.y * w1.w + hv.z * w2.w + hv.w * w3.w;
        }
    }

    // relu + store + per-thread column partials
    float cs[4] = {0.f, 0.f, 0.f, 0.f};
    float cq[4] = {0.f, 0.f, 0.f, 0.f};
    #pragma unroll
    for (int p = 0; p < 2; ++p) {
        const int node = base + hw * 2 + p;
        if (node < N) {
            float4 o;
            o.x = fmaxf(acc2[p][0], 0.f);
            o.y = fmaxf(acc2[p][1], 0.f);
            o.z = fmaxf(acc2[p][2], 0.f);
            o.w = fmaxf(acc2[p][3], 0.f);
            *(float4*)(out1 + (long)node * D + col) = o;
            cs[0] += o.x;     cs[1] += o.y;     cs[2] += o.z;     cs[3] += o.w;
            cq[0] += o.x*o.x; cq[1] += o.y*o.y; cq[2] += o.z*o.z; cq[3] += o.w*o.w;
        }
    }
    // fold lane^32 (same cg, the wave's other slot) -> lanes 0..31 hold the wave's 4-node partials
    #pragma unroll
    for (int c = 0; c < 4; ++c) {
        cs[c] += __shfl_xor(cs[c], 32);
        cq[c] += __shfl_xor(cq[c], 32);
    }

    __syncthreads();               // all h reads done; safe to reuse h as stats scratch
    float* ls = &h[0][0];          // ls[wave][128] sums, ls[8+wave][128] sumsqs
    const int wave = t >> 6;
    const int lane = t & 63;
    if (lane < 32) {
        *(float4*)&ls[wave * D + col]       = make_float4(cs[0], cs[1], cs[2], cs[3]);
        *(float4*)&ls[(8 + wave) * D + col] = make_float4(cq[0], cq[1], cq[2], cq[3]);
    }
    __syncthreads();
    if (t < D) {
        float s = 0.f;
        #pragma unroll
        for (int w = 0; w < 8; ++w) s += ls[w * D + t];
        atomicAdd(&stats[t], s);
    } else if (t < TWO_D) {
        const int j = t - D;
        float q = 0.f;
        #pragma unroll
        for (int w = 0; w < 8; ++w) q += ls[(8 + w) * D + j];
        atomicAdd(&stats[D + j], q);
    }
}

// ---------------- K2: batchnorm finalize + row L2 normalize (in-place on d_out) ----------------
__global__ __launch_bounds__(256) void k_final(
    float* __restrict__ out,
    const float* __restrict__ stats,
    const float* __restrict__ gamma,
    const float* __restrict__ beta,
    int N)
{
    __shared__ float scale[D];
    __shared__ float shift[D];
    const int t = threadIdx.x;
    if (t < D) {
        const float invN = 1.0f / (float)N;
        const float mu = stats[t] * invN;
        const float var = stats[D + t] * invN - mu * mu;
        const float sc = gamma[t] * rsqrtf(var + BN_EPS_C);
        scale[t] = sc;
        shift[t] = beta[t] - mu * sc;
    }
    __syncthreads();

    const int row = blockIdx.x * 8 + (t >> 5);
    const int l = t & 31;
    if (row < N) {
        float4 x = *(float4*)(out + (long)row * D + 4 * l);
        const float4 s4 = *(const float4*)&scale[4 * l];
        const float4 f4 = *(const float4*)&shift[4 * l];
        float4 y;
        y.x = x.x * s4.x + f4.x;
        y.y = x.y * s4.y + f4.y;
        y.z = x.z * s4.z + f4.z;
        y.w = x.w * s4.w + f4.w;
        float ss = y.x*y.x + y.y*y.y + y.z*y.z + y.w*y.w;
        #pragma unroll
        for (int m = 16; m >= 1; m >>= 1) ss += __shfl_xor(ss, m);
        const float inv = 1.0f / (sqrtf(ss) + NORM_EPS_C);
        y.x *= inv; y.y *= inv; y.z *= inv; y.w *= inv;
        *(float4*)(out + (long)row * D + 4 * l) = y;
    }
}

extern "C" void kernel_launch(void* const* d_in, const int* in_sizes, int n_in,
                              void* d_out, int out_size, void* d_ws, size_t ws_size,
                              hipStream_t stream) {
    const float* feat      = (const float*)d_in[0];
    const int*   self_idx  = (const int*)d_in[1];
    const int*   neigh_idx = (const int*)d_in[2];
    const float* W         = (const float*)d_in[3];
    const float* b         = (const float*)d_in[4];
    const float* gamma     = (const float*)d_in[5];
    const float* beta      = (const float*)d_in[6];
    float* out = (float*)d_out;
    const int N = in_sizes[1];

    float* Wt    = (float*)d_ws;          // 256*128 floats
    float* stats = Wt + TWO_D * D;        // 256 floats

    k_prep<<<TWO_D, D, 0, stream>>>(W, Wt, stats);
    k_main<<<(N + NPB - 1) / NPB, 512, 0, stream>>>(feat, self_idx, neigh_idx, Wt, b, out, stats, N);
    k_final<<<(N + 7) / 8, 256, 0, stream>>>(out, stats, gamma, beta, N);
}

// Round 4
// 178.320 us; speedup vs baseline: 1.0647x; 1.0647x over previous
//
#include <hip/hip_runtime.h>
#include <math.h>

#define D 128
#define TWO_D 256
#define S_NEIGH 25
#define NPB 16          // nodes per block in k_main
#define HPAD 260        // padded h row (float4-aligned, breaks pow2 stride)

static constexpr float BN_EPS_C = 1e-5f;
static constexpr float NORM_EPS_C = 1e-6f;

// ---------------- K0: transpose W [128][256] -> Wt [256][128]; zero stats ----------------
__global__ void k_prep(const float* __restrict__ W,
                       float* __restrict__ Wt,
                       float* __restrict__ stats) {
    const int k = blockIdx.x;    // 0..255
    const int j = threadIdx.x;   // 0..127
    Wt[k * D + j] = W[j * TWO_D + k];
    if (k < 2) stats[k * D + j] = 0.0f;
}

// ---------------- K1: gather + mean-agg + linear + relu + column stats ----------------
// 256 threads, 16 nodes/block. LDS ~18.3KB -> 8 blocks/CU -> 32 waves/CU @ VGPR<=64
__global__ __launch_bounds__(256, 4) void k_main(
    const float* __restrict__ feat,
    const int* __restrict__ self_idx,
    const int* __restrict__ neigh_idx,
    const float* __restrict__ Wt,
    const float* __restrict__ bias,
    float* __restrict__ out1,     // [N][128] pre-norm output (uses d_out)
    float* __restrict__ stats,    // [0..127]=sum, [128..255]=sumsq
    int N)
{
    __shared__ float h[NPB][HPAD];            // 16640 B; reused for stats partials later
    __shared__ int   s_nidx[NPB * S_NEIGH];   // 400 ints
    __shared__ int   s_sidx[NPB];

    const int t = threadIdx.x;
    const int base = blockIdx.x * NPB;
    const int nvalid = min(NPB, N - base);

    // ---- stage indices into LDS: one coalesced sweep ----
    {
        const int V = nvalid * S_NEIGH;
        const long goff = (long)base * S_NEIGH;     // base*25 ; base=16*bid -> 16B aligned
        if (t < (NPB * S_NEIGH) / 4) {              // 100 int4 loaders
            const int e0 = 4 * t;
            if (e0 + 3 < V) {
                ((int4*)s_nidx)[t] = ((const int4*)(neigh_idx + goff))[t];
            } else {
                #pragma unroll
                for (int e = 0; e < 4; ++e)
                    if (e0 + e < V) s_nidx[e0 + e] = neigh_idx[goff + e0 + e];
            }
        } else if (t < (NPB * S_NEIGH) / 4 + NPB) {
            const int i = t - (NPB * S_NEIGH) / 4;
            if (i < nvalid) s_sidx[i] = self_idx[base + i];
        }
    }
    __syncthreads();

    // ---- gather: each half-wave (32 lanes x float4) owns 2 nodes; 8-deep batched loads ----
    const int hw = t >> 5;        // 0..7
    const int l32 = t & 31;
    const int col = 4 * l32;
    const float* fcol = feat + col;
    #pragma unroll
    for (int p = 0; p < 2; ++p) {
        const int n = hw * 2 + p;
        if (n < nvalid) {
            const int* nid = s_nidx + n * S_NEIGH;
            float4 buf[8];
            float4 sf = *(const float4*)(fcol + (long)s_sidx[n] * D);
            float4 acc = make_float4(0.f, 0.f, 0.f, 0.f);
            #pragma unroll
            for (int b = 0; b < 3; ++b) {
                #pragma unroll
                for (int u = 0; u < 8; ++u)
                    buf[u] = *(const float4*)(fcol + (long)nid[b * 8 + u] * D);
                #pragma unroll
                for (int u = 0; u < 8; ++u) {
                    acc.x += buf[u].x; acc.y += buf[u].y;
                    acc.z += buf[u].z; acc.w += buf[u].w;
                }
            }
            const float4 f24 = *(const float4*)(fcol + (long)nid[24] * D);
            acc.x += f24.x; acc.y += f24.y; acc.z += f24.z; acc.w += f24.w;
            const float r = 1.0f / S_NEIGH;
            acc.x *= r; acc.y *= r; acc.z *= r; acc.w *= r;
            *(float4*)&h[n][col]     = sf;    // h[0:128] = self
            *(float4*)&h[n][D + col] = acc;   // h[128:256] = mean-agg
        }
    }
    __syncthreads();

    // ---- GEMM: out[n][j] = relu(b[j] + sum_k h[n][k]*Wt[k][j]) ----
    // thread: cols 4*l32..4*l32+3 ; nodes hw*2, hw*2+1
    const float4 b4 = *(const float4*)(bias + col);
    float acc2[2][4];
    #pragma unroll
    for (int p = 0; p < 2; ++p) {
        acc2[p][0] = b4.x; acc2[p][1] = b4.y; acc2[p][2] = b4.z; acc2[p][3] = b4.w;
    }

    for (int k = 0; k < TWO_D; k += 4) {
        const float4 w0 = *(const float4*)(Wt + (long)(k + 0) * D + col);
        const float4 w1 = *(const float4*)(Wt + (long)(k + 1) * D + col);
        const float4 w2 = *(const float4*)(Wt + (long)(k + 2) * D + col);
        const float4 w3 = *(const float4*)(Wt + (long)(k + 3) * D + col);
        #pragma unroll
        for (int p = 0; p < 2; ++p) {
            const float4 hv = *(const float4*)&h[hw * 2 + p][k];
            acc2[p][0] += hv.x * w0.x + hv.y * w1.x + hv.z * w2.x + hv.w * w3.x;
            acc2[p][1] += hv.x * w0.y + hv.y * w1.y + hv.z * w2.y + hv.w * w3.y;
            acc2[p][2] += hv.x * w0.z + hv.y * w1.z + hv.z * w2.z + hv.w * w3.z;
            acc2[p][3] += hv.x * w0.w + hv.y * w1.w + hv.z * w2.w + hv.w * w3.w;
        }
    }

    // relu + store + per-thread column partials
    float cs[4] = {0.f, 0.f, 0.f, 0.f};
    float cq[4] = {0.f, 0.f, 0.f, 0.f};
    #pragma unroll
    for (int p = 0; p < 2; ++p) {
        const int node = base + hw * 2 + p;
        if (node < N) {
            float4 o;
            o.x = fmaxf(acc2[p][0], 0.f);
            o.y = fmaxf(acc2[p][1], 0.f);
            o.z = fmaxf(acc2[p][2], 0.f);
            o.w = fmaxf(acc2[p][3], 0.f);
            *(float4*)(out1 + (long)node * D + col) = o;
            cs[0] += o.x;     cs[1] += o.y;     cs[2] += o.z;     cs[3] += o.w;
            cq[0] += o.x*o.x; cq[1] += o.y*o.y; cq[2] += o.z*o.z; cq[3] += o.w*o.w;
        }
    }
    // fold lane^32 (same cols, the wave's other node-pair) -> lanes 0..31 hold wave partials
    #pragma unroll
    for (int c = 0; c < 4; ++c) {
        cs[c] += __shfl_xor(cs[c], 32);
        cq[c] += __shfl_xor(cq[c], 32);
    }

    __syncthreads();               // all h reads done; safe to reuse h as stats scratch
    float* ls = &h[0][0];          // ls[wave][128] sums, ls[4+wave][128] sumsqs
    const int wave = t >> 6;       // 0..3
    const int lane = t & 63;
    if (lane < 32) {
        *(float4*)&ls[wave * D + col]       = make_float4(cs[0], cs[1], cs[2], cs[3]);
        *(float4*)&ls[(4 + wave) * D + col] = make_float4(cq[0], cq[1], cq[2], cq[3]);
    }
    __syncthreads();
    if (t < D) {
        float s = 0.f;
        #pragma unroll
        for (int w = 0; w < 4; ++w) s += ls[w * D + t];
        atomicAdd(&stats[t], s);
    } else {
        const int j = t - D;
        float q = 0.f;
        #pragma unroll
        for (int w = 0; w < 4; ++w) q += ls[(4 + w) * D + j];
        atomicAdd(&stats[D + j], q);
    }
}

// ---------------- K2: batchnorm finalize + row L2 normalize (in-place on d_out) ----------------
__global__ __launch_bounds__(256) void k_final(
    float* __restrict__ out,
    const float* __restrict__ stats,
    const float* __restrict__ gamma,
    const float* __restrict__ beta,
    int N)
{
    __shared__ float scale[D];
    __shared__ float shift[D];
    const int t = threadIdx.x;
    if (t < D) {
        const float invN = 1.0f / (float)N;
        const float mu = stats[t] * invN;
        const float var = stats[D + t] * invN - mu * mu;
        const float sc = gamma[t] * rsqrtf(var + BN_EPS_C);
        scale[t] = sc;
        shift[t] = beta[t] - mu * sc;
    }
    __syncthreads();

    const int row = blockIdx.x * 8 + (t >> 5);
    const int l = t & 31;
    if (row < N) {
        float4 x = *(float4*)(out + (long)row * D + 4 * l);
        const float4 s4 = *(const float4*)&scale[4 * l];
        const float4 f4 = *(const float4*)&shift[4 * l];
        float4 y;
        y.x = x.x * s4.x + f4.x;
        y.y = x.y * s4.y + f4.y;
        y.z = x.z * s4.z + f4.z;
        y.w = x.w * s4.w + f4.w;
        float ss = y.x*y.x + y.y*y.y + y.z*y.z + y.w*y.w;
        #pragma unroll
        for (int m = 16; m >= 1; m >>= 1) ss += __shfl_xor(ss, m);
        const float inv = 1.0f / (sqrtf(ss) + NORM_EPS_C);
        y.x *= inv; y.y *= inv; y.z *= inv; y.w *= inv;
        *(float4*)(out + (long)row * D + 4 * l) = y;
    }
}

extern "C" void kernel_launch(void* const* d_in, const int* in_sizes, int n_in,
                              void* d_out, int out_size, void* d_ws, size_t ws_size,
                              hipStream_t stream) {
    const float* feat      = (const float*)d_in[0];
    const int*   self_idx  = (const int*)d_in[1];
    const int*   neigh_idx = (const int*)d_in[2];
    const float* W         = (const float*)d_in[3];
    const float* b         = (const float*)d_in[4];
    const float* gamma     = (const float*)d_in[5];
    const float* beta      = (const float*)d_in[6];
    float* out = (float*)d_out;
    const int N = in_sizes[1];

    float* Wt    = (float*)d_ws;          // 256*128 floats
    float* stats = Wt + TWO_D * D;        // 256 floats

    k_prep<<<TWO_D, D, 0, stream>>>(W, Wt, stats);
    k_main<<<(N + NPB - 1) / NPB, 256, 0, stream>>>(feat, self_idx, neigh_idx, Wt, b, out, stats, N);
    k_final<<<(N + 7) / 8, 256, 0, stream>>>(out, stats, gamma, beta, N);
}

// Round 5
// 119.912 us; speedup vs baseline: 1.5833x; 1.4871x over previous
//
#include <hip/hip_runtime.h>
#include <math.h>

typedef __attribute__((ext_vector_type(8))) short short8;
typedef __attribute__((ext_vector_type(4))) float f32x4;
typedef unsigned short ushort_t;
typedef unsigned int uint_t;

#define D 128
#define TWO_D 256
#define S_NEIGH 25

static constexpr float BN_EPS_C = 1e-5f;
static constexpr float NORM_EPS_C = 1e-6f;

__device__ __forceinline__ uint_t f2bf_bits(float f) {
    // round-to-nearest-even bf16 (inputs are finite)
    uint_t u = __float_as_uint(f);
    return (u + 0x7FFFu + ((u >> 16) & 1u)) >> 16;
}

// ---------------- P0: W fp32 [128][256] -> bf16 (same layout); zero stats ----------------
__global__ void k_prep_w(const float* __restrict__ W, ushort_t* __restrict__ Wb,
                         float* __restrict__ stats) {
    const int i = blockIdx.x * 256 + threadIdx.x;   // grid 128 -> 32768
    Wb[i] = (ushort_t)f2bf_bits(W[i]);
    if (blockIdx.x == 0) stats[threadIdx.x] = 0.0f;
}

// ---------------- P1: feat fp32 -> bf16 table (full path only) ----------------
__global__ __launch_bounds__(256) void k_conv(const float* __restrict__ feat,
                                              ushort_t* __restrict__ feat16) {
    // 25.6M elems, 8 per thread -> grid 12500
    const long i0 = ((long)blockIdx.x * 256 + threadIdx.x) * 8;
    const float4 f0 = *(const float4*)(feat + i0);
    const float4 f1 = *(const float4*)(feat + i0 + 4);
    uint_t o[4];
    o[0] = f2bf_bits(f0.x) | (f2bf_bits(f0.y) << 16);
    o[1] = f2bf_bits(f0.z) | (f2bf_bits(f0.w) << 16);
    o[2] = f2bf_bits(f1.x) | (f2bf_bits(f1.y) << 16);
    o[3] = f2bf_bits(f1.z) | (f2bf_bits(f1.w) << 16);
    *(uint4*)(feat16 + i0) = *(uint4*)o;
}

// ---------------- G: gather + mean-agg -> h16 [Nr][256] bf16 (bf16 source) ----------------
// 64 nodes/block, 16-lane groups x 16B; 5x5 batched loads for MLP.
__global__ __launch_bounds__(256, 4) void k_gather16(
    const ushort_t* __restrict__ feat16,
    const int* __restrict__ self_idx,
    const int* __restrict__ neigh_idx,
    ushort_t* __restrict__ h16, int N)
{
    __shared__ int s_nidx[64 * S_NEIGH];
    __shared__ int s_sidx[64];
    const int t = threadIdx.x;
    const int base = blockIdx.x * 64;
    const int nvalid = min(64, N - base);
    const int V = nvalid * S_NEIGH;
    const long goff = (long)base * S_NEIGH;
    for (int i = t; i < (64 * S_NEIGH) / 4; i += 256) {
        const int e0 = 4 * i;
        if (e0 + 3 < V) {
            ((int4*)s_nidx)[i] = *(const int4*)(neigh_idx + goff + e0);
        } else {
            #pragma unroll
            for (int e = 0; e < 4; ++e)
                if (e0 + e < V) s_nidx[e0 + e] = neigh_idx[goff + e0 + e];
        }
    }
    if (t < 64 && t < nvalid) s_sidx[t] = self_idx[base + t];
    __syncthreads();

    const int g = t >> 4;          // 0..15
    const int l16 = t & 15;
    const int eoff = l16 * 8;      // element offset within a 128-elem row
    #pragma unroll
    for (int rep = 0; rep < 4; ++rep) {
        const int n = rep * 16 + g;
        if (n < nvalid) {
            const long gn = base + n;
            const uint4 sf = *(const uint4*)(feat16 + (long)s_sidx[n] * D + eoff);
            *(uint4*)(h16 + gn * TWO_D + eoff) = sf;          // self -> cols 0..127
            const int* nid = s_nidx + n * S_NEIGH;
            float acc[8] = {0.f,0.f,0.f,0.f,0.f,0.f,0.f,0.f};
            #pragma unroll
            for (int b = 0; b < 5; ++b) {
                uint4 buf[5];
                #pragma unroll
                for (int u = 0; u < 5; ++u)
                    buf[u] = *(const uint4*)(feat16 + (long)nid[b * 5 + u] * D + eoff);
                #pragma unroll
                for (int u = 0; u < 5; ++u) {
                    const uint_t* pu = (const uint_t*)&buf[u];
                    #pragma unroll
                    for (int j = 0; j < 4; ++j) {
                        const uint_t w = pu[j];
                        acc[2 * j]     += __uint_as_float(w << 16);
                        acc[2 * j + 1] += __uint_as_float(w & 0xFFFF0000u);
                    }
                }
            }
            const float r = 1.0f / S_NEIGH;
            uint_t o[4];
            #pragma unroll
            for (int j = 0; j < 4; ++j)
                o[j] = f2bf_bits(acc[2 * j] * r) | (f2bf_bits(acc[2 * j + 1] * r) << 16);
            *(uint4*)(h16 + gn * TWO_D + D + eoff) = *(uint4*)o;  // agg -> cols 128..255
        }
    }
}

// ---------------- G32: same but gathers from fp32 feat (fallback, no conv table) ----------------
__global__ __launch_bounds__(256, 4) void k_gather32(
    const float* __restrict__ feat,
    const int* __restrict__ self_idx,
    const int* __restrict__ neigh_idx,
    ushort_t* __restrict__ h16, int N)
{
    __shared__ int s_nidx[64 * S_NEIGH];
    __shared__ int s_sidx[64];
    const int t = threadIdx.x;
    const int base = blockIdx.x * 64;
    const int nvalid = min(64, N - base);
    const int V = nvalid * S_NEIGH;
    const long goff = (long)base * S_NEIGH;
    for (int i = t; i < (64 * S_NEIGH) / 4; i += 256) {
        const int e0 = 4 * i;
        if (e0 + 3 < V) {
            ((int4*)s_nidx)[i] = *(const int4*)(neigh_idx + goff + e0);
        } else {
            #pragma unroll
            for (int e = 0; e < 4; ++e)
                if (e0 + e < V) s_nidx[e0 + e] = neigh_idx[goff + e0 + e];
        }
    }
    if (t < 64 && t < nvalid) s_sidx[t] = self_idx[base + t];
    __syncthreads();

    const int g = t >> 5;          // 0..7 (32-lane groups, float4 = 16B covers 512B row)
    const int l32 = t & 31;
    const int eoff = l32 * 4;
    #pragma unroll
    for (int rep = 0; rep < 8; ++rep) {
        const int n = rep * 8 + g;
        if (n < nvalid) {
            const long gn = base + n;
            const float4 sf = *(const float4*)(feat + (long)s_sidx[n] * D + eoff);
            uint_t so[2];
            so[0] = f2bf_bits(sf.x) | (f2bf_bits(sf.y) << 16);
            so[1] = f2bf_bits(sf.z) | (f2bf_bits(sf.w) << 16);
            *(uint2*)(h16 + gn * TWO_D + eoff) = *(uint2*)so;
            const int* nid = s_nidx + n * S_NEIGH;
            float a0 = 0.f, a1 = 0.f, a2 = 0.f, a3 = 0.f;
            #pragma unroll
            for (int b = 0; b < 5; ++b) {
                float4 buf[5];
                #pragma unroll
                for (int u = 0; u < 5; ++u)
                    buf[u] = *(const float4*)(feat + (long)nid[b * 5 + u] * D + eoff);
                #pragma unroll
                for (int u = 0; u < 5; ++u) {
                    a0 += buf[u].x; a1 += buf[u].y; a2 += buf[u].z; a3 += buf[u].w;
                }
            }
            const float r = 1.0f / S_NEIGH;
            uint_t o[2];
            o[0] = f2bf_bits(a0 * r) | (f2bf_bits(a1 * r) << 16);
            o[1] = f2bf_bits(a2 * r) | (f2bf_bits(a3 * r) << 16);
            *(uint2*)(h16 + gn * TWO_D + D + eoff) = *(uint2*)o;
        }
    }
}

// ---------------- M: MFMA GEMM out = relu(h16 @ Wb^T + b) + column stats ----------------
// 256 thr = 4 waves; 64 nodes/block (16/wave); N=128 cols = 8 n-tiles; K=256 = 8 k-steps.
// B (=W row-major: B[k][col]=W[col][k]) staged in LDS, XOR-swizzled 16B granules.
__global__ __launch_bounds__(256, 2) void k_gemm(
    const ushort_t* __restrict__ h16,
    const ushort_t* __restrict__ Wb,
    const float* __restrict__ bias,
    float* __restrict__ out1,
    float* __restrict__ stats,
    int N)
{
    __shared__ ushort_t lds_b[32768];      // 64 KB
    __shared__ float lds_s[4][D];
    __shared__ float lds_q[4][D];

    const int t = threadIdx.x;
    // stage Wb -> LDS with granule swizzle: granule g of row r stored at g ^ (r&7)
    #pragma unroll
    for (int it = 0; it < 16; ++it) {
        const int i = it * 256 + t;        // 0..4095 granules (16B each)
        const int row = i >> 5;
        const int gr  = i & 31;
        const uint4 v = *(const uint4*)(Wb + row * TWO_D + gr * 8);
        *(uint4*)(lds_b + row * TWO_D + ((gr ^ (row & 7)) * 8)) = v;
    }
    __syncthreads();

    const int wv = t >> 6;
    const int l  = t & 63;
    const int lm = l & 15;
    const int lh = l >> 4;                  // 0..3
    const int mb = blockIdx.x * 64 + wv * 16;

    // A fragments for this wave's 16 nodes, all K (8 k-steps) in regs
    short8 a[8];
    const long arow = (long)(mb + lm) * TWO_D;
    #pragma unroll
    for (int ks = 0; ks < 8; ++ks)
        a[ks] = *(const short8*)(h16 + arow + ks * 32 + lh * 8);

    f32x4 acc[8];
    #pragma unroll
    for (int nt = 0; nt < 8; ++nt) {
        const float bc = bias[nt * 16 + lm];
        acc[nt] = (f32x4){bc, bc, bc, bc};
    }

    #pragma unroll
    for (int nt = 0; nt < 8; ++nt) {
        const int colrow = nt * 16 + lm;    // storage row in lds_b = output column
        #pragma unroll
        for (int ks = 0; ks < 8; ++ks) {
            const short8 b = *(const short8*)(lds_b + colrow * TWO_D +
                                              (((ks * 4 + lh) ^ (l & 7)) * 8));
            acc[nt] = __builtin_amdgcn_mfma_f32_16x16x32_bf16(a[ks], b, acc[nt], 0, 0, 0);
        }
    }

    // epilogue: relu + store + column partial sums (C layout: col=lm, row=lh*4+r)
    #pragma unroll
    for (int nt = 0; nt < 8; ++nt) {
        float cs = 0.f, cq = 0.f;
        #pragma unroll
        for (int r = 0; r < 4; ++r) {
            const int node = mb + lh * 4 + r;
            const float v = fmaxf(acc[nt][r], 0.f);
            if (node < N) {
                out1[(long)node * D + nt * 16 + lm] = v;
                cs += v; cq += v * v;
            }
        }
        cs += __shfl_xor(cs, 16); cq += __shfl_xor(cq, 16);
        cs += __shfl_xor(cs, 32); cq += __shfl_xor(cq, 32);
        if (l < 16) { lds_s[wv][nt * 16 + l] = cs; lds_q[wv][nt * 16 + l] = cq; }
    }
    __syncthreads();
    if (t < D) {
        atomicAdd(&stats[t], lds_s[0][t] + lds_s[1][t] + lds_s[2][t] + lds_s[3][t]);
    } else {
        const int j = t - D;
        atomicAdd(&stats[D + j], lds_q[0][j] + lds_q[1][j] + lds_q[2][j] + lds_q[3][j]);
    }
}

// ---------------- F: batchnorm finalize + row L2 normalize (in-place on d_out) ----------------
__global__ __launch_bounds__(256) void k_final(
    float* __restrict__ out,
    const float* __restrict__ stats,
    const float* __restrict__ gamma,
    const float* __restrict__ beta,
    int N)
{
    __shared__ float scale[D];
    __shared__ float shift[D];
    const int t = threadIdx.x;
    if (t < D) {
        const float invN = 1.0f / (float)N;
        const float mu = stats[t] * invN;
        const float var = stats[D + t] * invN - mu * mu;
        const float sc = gamma[t] * rsqrtf(var + BN_EPS_C);
        scale[t] = sc;
        shift[t] = beta[t] - mu * sc;
    }
    __syncthreads();

    const int row = blockIdx.x * 8 + (t >> 5);
    const int l = t & 31;
    if (row < N) {
        float4 x = *(float4*)(out + (long)row * D + 4 * l);
        const float4 s4 = *(const float4*)&scale[4 * l];
        const float4 f4 = *(const float4*)&shift[4 * l];
        float4 y;
        y.x = x.x * s4.x + f4.x;
        y.y = x.y * s4.y + f4.y;
        y.z = x.z * s4.z + f4.z;
        y.w = x.w * s4.w + f4.w;
        float ss = y.x*y.x + y.y*y.y + y.z*y.z + y.w*y.w;
        #pragma unroll
        for (int m = 16; m >= 1; m >>= 1) ss += __shfl_xor(ss, m);
        const float inv = 1.0f / (sqrtf(ss) + NORM_EPS_C);
        y.x *= inv; y.y *= inv; y.z *= inv; y.w *= inv;
        *(float4*)(out + (long)row * D + 4 * l) = y;
    }
}

extern "C" void kernel_launch(void* const* d_in, const int* in_sizes, int n_in,
                              void* d_out, int out_size, void* d_ws, size_t ws_size,
                              hipStream_t stream) {
    const float* feat      = (const float*)d_in[0];
    const int*   self_idx  = (const int*)d_in[1];
    const int*   neigh_idx = (const int*)d_in[2];
    const float* W         = (const float*)d_in[3];
    const float* b         = (const float*)d_in[4];
    const float* gamma     = (const float*)d_in[5];
    const float* beta      = (const float*)d_in[6];
    float* out = (float*)d_out;
    const int N = in_sizes[1];                 // 50000
    const long n_total = in_sizes[0] / D;      // 200000
    const int nblk = (N + 63) / 64;            // 782
    const long nr = (long)nblk * 64;           // 50048 rounded rows for h16

    const size_t feat16_bytes = (size_t)n_total * D * 2;        // 51.2 MB
    const size_t h16_bytes    = (size_t)nr * TWO_D * 2;         // 25.6 MB
    const size_t wb_bytes     = (size_t)D * TWO_D * 2;          // 64 KB
    const size_t stats_bytes  = 256 * 4;
    const bool full = ws_size >= feat16_bytes + h16_bytes + wb_bytes + stats_bytes;

    char* p = (char*)d_ws;
    ushort_t* feat16 = nullptr;
    if (full) { feat16 = (ushort_t*)p; p += feat16_bytes; }
    ushort_t* h16 = (ushort_t*)p; p += h16_bytes;
    ushort_t* Wb  = (ushort_t*)p; p += wb_bytes;
    float* stats  = (float*)p;

    k_prep_w<<<D * TWO_D / 256, 256, 0, stream>>>(W, Wb, stats);
    if (full) {
        k_conv<<<(int)(n_total * D / (256 * 8)), 256, 0, stream>>>(feat, feat16);
        k_gather16<<<nblk, 256, 0, stream>>>(feat16, self_idx, neigh_idx, h16, N);
    } else {
        k_gather32<<<nblk, 256, 0, stream>>>(feat, self_idx, neigh_idx, h16, N);
    }
    k_gemm<<<nblk, 256, 0, stream>>>(h16, Wb, b, out, stats, N);
    k_final<<<(N + 7) / 8, 256, 0, stream>>>(out, stats, gamma, beta, N);
}

// Round 6
// 104.761 us; speedup vs baseline: 1.8123x; 1.1446x over previous
//
#include <hip/hip_runtime.h>
#include <math.h>

typedef __attribute__((ext_vector_type(8))) short short8;
typedef __attribute__((ext_vector_type(4))) float f32x4;
typedef unsigned short ushort_t;
typedef unsigned int uint_t;

#define D 128
#define TWO_D 256
#define S_NEIGH 25

static constexpr float BN_EPS_C = 1e-5f;
static constexpr float NORM_EPS_C = 1e-6f;

__device__ __forceinline__ uint_t f2bf_bits(float f) {
    // round-to-nearest-even bf16 (inputs are finite)
    uint_t u = __float_as_uint(f);
    return (u + 0x7FFFu + ((u >> 16) & 1u)) >> 16;
}

__device__ __forceinline__ void conv8(const float* __restrict__ src, ushort_t* __restrict__ dst) {
    const float4 f0 = *(const float4*)(src);
    const float4 f1 = *(const float4*)(src + 4);
    uint_t o[4];
    o[0] = f2bf_bits(f0.x) | (f2bf_bits(f0.y) << 16);
    o[1] = f2bf_bits(f0.z) | (f2bf_bits(f0.w) << 16);
    o[2] = f2bf_bits(f1.x) | (f2bf_bits(f1.y) << 16);
    o[3] = f2bf_bits(f1.z) | (f2bf_bits(f1.w) << 16);
    *(uint4*)(dst) = *(uint4*)o;
}

// ---------------- P: feat fp32 -> bf16 table; W -> bf16; zero stats (fused) ----------------
__global__ __launch_bounds__(256) void k_conv(const float* __restrict__ feat,
                                              ushort_t* __restrict__ feat16,
                                              const float* __restrict__ W,
                                              ushort_t* __restrict__ Wb,
                                              float* __restrict__ stats) {
    const long i0 = ((long)blockIdx.x * 256 + threadIdx.x) * 8;
    conv8(feat + i0, feat16 + i0);
    if (blockIdx.x < 16) {                       // 16 blocks * 2048 = 32768 W elems
        conv8(W + i0, Wb + i0);
    }
    if (blockIdx.x == 16 && threadIdx.x < 256) stats[threadIdx.x] = 0.0f;
}

// ---------------- G: gather + mean-agg -> h16 [Nr][256] bf16 (bf16 source) ----------------
// 64 nodes/block, 16-lane groups x 16B; 8-deep batched loads, dual accumulate chains.
__global__ __launch_bounds__(256, 4) void k_gather16(
    const ushort_t* __restrict__ feat16,
    const int* __restrict__ self_idx,
    const int* __restrict__ neigh_idx,
    ushort_t* __restrict__ h16, int N)
{
    __shared__ int s_nidx[64 * S_NEIGH];
    __shared__ int s_sidx[64];
    const int t = threadIdx.x;
    const int base = blockIdx.x * 64;
    const int nvalid = min(64, N - base);
    const int V = nvalid * S_NEIGH;
    const long goff = (long)base * S_NEIGH;
    for (int i = t; i < (64 * S_NEIGH) / 4; i += 256) {
        const int e0 = 4 * i;
        if (e0 + 3 < V) {
            ((int4*)s_nidx)[i] = *(const int4*)(neigh_idx + goff + e0);
        } else {
            #pragma unroll
            for (int e = 0; e < 4; ++e)
                if (e0 + e < V) s_nidx[e0 + e] = neigh_idx[goff + e0 + e];
        }
    }
    if (t < 64 && t < nvalid) s_sidx[t] = self_idx[base + t];
    __syncthreads();

    const int g = t >> 4;          // 0..15
    const int l16 = t & 15;
    const int eoff = l16 * 8;      // element offset within a 128-elem row
    #pragma unroll
    for (int rep = 0; rep < 4; ++rep) {
        const int n = rep * 16 + g;
        if (n < nvalid) {
            const long gn = base + n;
            const uint4 sf = *(const uint4*)(feat16 + (long)s_sidx[n] * D + eoff);
            *(uint4*)(h16 + gn * TWO_D + eoff) = sf;          // self -> cols 0..127
            const int* nid = s_nidx + n * S_NEIGH;
            float ae[8] = {0.f,0.f,0.f,0.f,0.f,0.f,0.f,0.f};  // even-u chain
            float ao[8] = {0.f,0.f,0.f,0.f,0.f,0.f,0.f,0.f};  // odd-u chain
            #pragma unroll
            for (int b = 0; b < 3; ++b) {
                uint4 buf[8];
                #pragma unroll
                for (int u = 0; u < 8; ++u)
                    buf[u] = *(const uint4*)(feat16 + (long)nid[b * 8 + u] * D + eoff);
                #pragma unroll
                for (int u = 0; u < 8; ++u) {
                    const uint_t* pu = (const uint_t*)&buf[u];
                    float* ac = (u & 1) ? ao : ae;
                    #pragma unroll
                    for (int j = 0; j < 4; ++j) {
                        const uint_t w = pu[j];
                        ac[2 * j]     += __uint_as_float(w << 16);
                        ac[2 * j + 1] += __uint_as_float(w & 0xFFFF0000u);
                    }
                }
            }
            {   // neighbor 24
                const uint4 f24 = *(const uint4*)(feat16 + (long)nid[24] * D + eoff);
                const uint_t* pu = (const uint_t*)&f24;
                #pragma unroll
                for (int j = 0; j < 4; ++j) {
                    const uint_t w = pu[j];
                    ae[2 * j]     += __uint_as_float(w << 16);
                    ae[2 * j + 1] += __uint_as_float(w & 0xFFFF0000u);
                }
            }
            const float r = 1.0f / S_NEIGH;
            uint_t o[4];
            #pragma unroll
            for (int j = 0; j < 4; ++j)
                o[j] = f2bf_bits((ae[2 * j] + ao[2 * j]) * r) |
                       (f2bf_bits((ae[2 * j + 1] + ao[2 * j + 1]) * r) << 16);
            *(uint4*)(h16 + gn * TWO_D + D + eoff) = *(uint4*)o;  // agg -> cols 128..255
        }
    }
}

// ---------------- G32: fallback gather from fp32 feat (no conv table) ----------------
__global__ __launch_bounds__(256, 4) void k_gather32(
    const float* __restrict__ feat,
    const int* __restrict__ self_idx,
    const int* __restrict__ neigh_idx,
    ushort_t* __restrict__ h16, int N)
{
    __shared__ int s_nidx[64 * S_NEIGH];
    __shared__ int s_sidx[64];
    const int t = threadIdx.x;
    const int base = blockIdx.x * 64;
    const int nvalid = min(64, N - base);
    const int V = nvalid * S_NEIGH;
    const long goff = (long)base * S_NEIGH;
    for (int i = t; i < (64 * S_NEIGH) / 4; i += 256) {
        const int e0 = 4 * i;
        if (e0 + 3 < V) {
            ((int4*)s_nidx)[i] = *(const int4*)(neigh_idx + goff + e0);
        } else {
            #pragma unroll
            for (int e = 0; e < 4; ++e)
                if (e0 + e < V) s_nidx[e0 + e] = neigh_idx[goff + e0 + e];
        }
    }
    if (t < 64 && t < nvalid) s_sidx[t] = self_idx[base + t];
    __syncthreads();

    const int g = t >> 5;
    const int l32 = t & 31;
    const int eoff = l32 * 4;
    #pragma unroll
    for (int rep = 0; rep < 8; ++rep) {
        const int n = rep * 8 + g;
        if (n < nvalid) {
            const long gn = base + n;
            const float4 sf = *(const float4*)(feat + (long)s_sidx[n] * D + eoff);
            uint_t so[2];
            so[0] = f2bf_bits(sf.x) | (f2bf_bits(sf.y) << 16);
            so[1] = f2bf_bits(sf.z) | (f2bf_bits(sf.w) << 16);
            *(uint2*)(h16 + gn * TWO_D + eoff) = *(uint2*)so;
            const int* nid = s_nidx + n * S_NEIGH;
            float a0 = 0.f, a1 = 0.f, a2 = 0.f, a3 = 0.f;
            #pragma unroll
            for (int b = 0; b < 5; ++b) {
                float4 buf[5];
                #pragma unroll
                for (int u = 0; u < 5; ++u)
                    buf[u] = *(const float4*)(feat + (long)nid[b * 5 + u] * D + eoff);
                #pragma unroll
                for (int u = 0; u < 5; ++u) {
                    a0 += buf[u].x; a1 += buf[u].y; a2 += buf[u].z; a3 += buf[u].w;
                }
            }
            const float r = 1.0f / S_NEIGH;
            uint_t o[2];
            o[0] = f2bf_bits(a0 * r) | (f2bf_bits(a1 * r) << 16);
            o[1] = f2bf_bits(a2 * r) | (f2bf_bits(a3 * r) << 16);
            *(uint2*)(h16 + gn * TWO_D + D + eoff) = *(uint2*)o;
        }
    }
}

// ---------------- M: MFMA GEMM out = relu(h16 @ Wb^T + b) + column stats ----------------
// 512 thr = 8 waves; 128 nodes/block (16/wave); 128 cols = 8 n-tiles; K=256 = 8 k-steps.
// B (=W row-major) staged in LDS once per block, XOR-swizzled 16B granules.
__global__ __launch_bounds__(512, 2) void k_gemm(
    const ushort_t* __restrict__ h16,
    const ushort_t* __restrict__ Wb,
    const float* __restrict__ bias,
    float* __restrict__ out1,
    float* __restrict__ stats,
    int N)
{
    __shared__ ushort_t lds_b[32768];      // 64 KB
    __shared__ float lds_s[8][D];
    __shared__ float lds_q[8][D];

    const int t = threadIdx.x;
    // stage Wb -> LDS with granule swizzle: granule g of row r stored at g ^ (r&7)
    #pragma unroll
    for (int it = 0; it < 8; ++it) {
        const int i = it * 512 + t;        // 0..4095 granules (16B each)
        const int row = i >> 5;
        const int gr  = i & 31;
        const uint4 v = *(const uint4*)(Wb + row * TWO_D + gr * 8);
        *(uint4*)(lds_b + row * TWO_D + ((gr ^ (row & 7)) * 8)) = v;
    }
    __syncthreads();

    const int wv = t >> 6;                  // 0..7
    const int l  = t & 63;
    const int lm = l & 15;
    const int lh = l >> 4;                  // 0..3
    const int mb = blockIdx.x * 128 + wv * 16;

    // A fragments for this wave's 16 nodes, all K (8 k-steps) in regs
    short8 a[8];
    const long arow = (long)(mb + lm) * TWO_D;
    #pragma unroll
    for (int ks = 0; ks < 8; ++ks)
        a[ks] = *(const short8*)(h16 + arow + ks * 32 + lh * 8);

    f32x4 acc[8];
    #pragma unroll
    for (int nt = 0; nt < 8; ++nt) {
        const float bc = bias[nt * 16 + lm];
        acc[nt] = (f32x4){bc, bc, bc, bc};
    }

    #pragma unroll
    for (int nt = 0; nt < 8; ++nt) {
        const int colrow = nt * 16 + lm;    // storage row in lds_b = output column
        #pragma unroll
        for (int ks = 0; ks < 8; ++ks) {
            const short8 b = *(const short8*)(lds_b + colrow * TWO_D +
                                              (((ks * 4 + lh) ^ (l & 7)) * 8));
            acc[nt] = __builtin_amdgcn_mfma_f32_16x16x32_bf16(a[ks], b, acc[nt], 0, 0, 0);
        }
    }

    // epilogue: relu + store + column partial sums (C layout: col=lm, row=lh*4+r)
    #pragma unroll
    for (int nt = 0; nt < 8; ++nt) {
        float cs = 0.f, cq = 0.f;
        #pragma unroll
        for (int r = 0; r < 4; ++r) {
            const int node = mb + lh * 4 + r;
            const float v = fmaxf(acc[nt][r], 0.f);
            if (node < N) {
                out1[(long)node * D + nt * 16 + lm] = v;
                cs += v; cq += v * v;
            }
        }
        cs += __shfl_xor(cs, 16); cq += __shfl_xor(cq, 16);
        cs += __shfl_xor(cs, 32); cq += __shfl_xor(cq, 32);
        if (l < 16) { lds_s[wv][nt * 16 + l] = cs; lds_q[wv][nt * 16 + l] = cq; }
    }
    __syncthreads();
    if (t < D) {
        float s = 0.f;
        #pragma unroll
        for (int w = 0; w < 8; ++w) s += lds_s[w][t];
        atomicAdd(&stats[t], s);
    } else if (t < TWO_D) {
        const int j = t - D;
        float q = 0.f;
        #pragma unroll
        for (int w = 0; w < 8; ++w) q += lds_q[w][j];
        atomicAdd(&stats[D + j], q);
    }
}

// ---------------- F: batchnorm finalize + row L2 normalize (in-place on d_out) ----------------
__global__ __launch_bounds__(256) void k_final(
    float* __restrict__ out,
    const float* __restrict__ stats,
    const float* __restrict__ gamma,
    const float* __restrict__ beta,
    int N)
{
    __shared__ float scale[D];
    __shared__ float shift[D];
    const int t = threadIdx.x;
    if (t < D) {
        const float invN = 1.0f / (float)N;
        const float mu = stats[t] * invN;
        const float var = stats[D + t] * invN - mu * mu;
        const float sc = gamma[t] * rsqrtf(var + BN_EPS_C);
        scale[t] = sc;
        shift[t] = beta[t] - mu * sc;
    }
    __syncthreads();

    const int row = blockIdx.x * 8 + (t >> 5);
    const int l = t & 31;
    if (row < N) {
        float4 x = *(float4*)(out + (long)row * D + 4 * l);
        const float4 s4 = *(const float4*)&scale[4 * l];
        const float4 f4 = *(const float4*)&shift[4 * l];
        float4 y;
        y.x = x.x * s4.x + f4.x;
        y.y = x.y * s4.y + f4.y;
        y.z = x.z * s4.z + f4.z;
        y.w = x.w * s4.w + f4.w;
        float ss = y.x*y.x + y.y*y.y + y.z*y.z + y.w*y.w;
        #pragma unroll
        for (int m = 16; m >= 1; m >>= 1) ss += __shfl_xor(ss, m);
        const float inv = 1.0f / (sqrtf(ss) + NORM_EPS_C);
        y.x *= inv; y.y *= inv; y.z *= inv; y.w *= inv;
        *(float4*)(out + (long)row * D + 4 * l) = y;
    }
}

extern "C" void kernel_launch(void* const* d_in, const int* in_sizes, int n_in,
                              void* d_out, int out_size, void* d_ws, size_t ws_size,
                              hipStream_t stream) {
    const float* feat      = (const float*)d_in[0];
    const int*   self_idx  = (const int*)d_in[1];
    const int*   neigh_idx = (const int*)d_in[2];
    const float* W         = (const float*)d_in[3];
    const float* b         = (const float*)d_in[4];
    const float* gamma     = (const float*)d_in[5];
    const float* beta      = (const float*)d_in[6];
    float* out = (float*)d_out;
    const int N = in_sizes[1];                 // 50000
    const long n_total = in_sizes[0] / D;      // 200000
    const int gblk = (N + 63) / 64;            // gather blocks (782)
    const int mblk = (N + 127) / 128;          // gemm blocks (391)
    const long nr = (long)mblk * 128;          // 50048 rounded rows for h16

    const size_t feat16_bytes = (size_t)n_total * D * 2;        // 51.2 MB
    const size_t h16_bytes    = (size_t)nr * TWO_D * 2;         // 25.6 MB
    const size_t wb_bytes     = (size_t)D * TWO_D * 2;          // 64 KB
    const size_t stats_bytes  = 256 * 4;
    const bool full = ws_size >= feat16_bytes + h16_bytes + wb_bytes + stats_bytes;

    char* p = (char*)d_ws;
    ushort_t* feat16 = nullptr;
    if (full) { feat16 = (ushort_t*)p; p += feat16_bytes; }
    ushort_t* h16 = (ushort_t*)p; p += h16_bytes;
    ushort_t* Wb  = (ushort_t*)p; p += wb_bytes;
    float* stats  = (float*)p;

    if (full) {
        k_conv<<<(int)(n_total * D / (256 * 8)), 256, 0, stream>>>(feat, feat16, W, Wb, stats);
        k_gather16<<<gblk, 256, 0, stream>>>(feat16, self_idx, neigh_idx, h16, N);
    } else {
        // fallback: W conversion + stats zero via a 129-block pass reusing k_conv on W only
        k_conv<<<16, 256, 0, stream>>>(W, Wb, W, Wb, stats);   // blocks 0..15 convert W (i0 < 32768)
        hipMemsetAsync(stats, 0, 256 * 4, stream);
        k_gather32<<<gblk, 256, 0, stream>>>(feat, self_idx, neigh_idx, h16, N);
    }
    k_gemm<<<mblk, 512, 0, stream>>>(h16, Wb, b, out, stats, N);
    k_final<<<(N + 7) / 8, 256, 0, stream>>>(out, stats, gamma, beta, N);
}

// Round 7
// 104.041 us; speedup vs baseline: 1.8248x; 1.0069x over previous
//
#include <hip/hip_runtime.h>
#include <math.h>

typedef __attribute__((ext_vector_type(8))) short short8;
typedef __attribute__((ext_vector_type(4))) float f32x4;
typedef unsigned short ushort_t;
typedef unsigned int uint_t;

#define D 128
#define TWO_D 256
#define S_NEIGH 25

static constexpr float BN_EPS_C = 1e-5f;
static constexpr float NORM_EPS_C = 1e-6f;

__device__ __forceinline__ uint_t f2bf_bits(float f) {
    // round-to-nearest-even bf16 (inputs are finite)
    uint_t u = __float_as_uint(f);
    return (u + 0x7FFFu + ((u >> 16) & 1u)) >> 16;
}

__device__ __forceinline__ void conv8(const float* __restrict__ src, ushort_t* __restrict__ dst) {
    const float4 f0 = *(const float4*)(src);
    const float4 f1 = *(const float4*)(src + 4);
    uint_t o[4];
    o[0] = f2bf_bits(f0.x) | (f2bf_bits(f0.y) << 16);
    o[1] = f2bf_bits(f0.z) | (f2bf_bits(f0.w) << 16);
    o[2] = f2bf_bits(f1.x) | (f2bf_bits(f1.y) << 16);
    o[3] = f2bf_bits(f1.z) | (f2bf_bits(f1.w) << 16);
    *(uint4*)(dst) = *(uint4*)o;
}

// ---------------- P: feat fp32 -> bf16 table; W -> bf16; zero stats (fused) ----------------
__global__ __launch_bounds__(256) void k_conv(const float* __restrict__ feat,
                                              ushort_t* __restrict__ feat16,
                                              const float* __restrict__ W,
                                              ushort_t* __restrict__ Wb,
                                              float* __restrict__ stats) {
    const long i0 = ((long)blockIdx.x * 256 + threadIdx.x) * 8;
    conv8(feat + i0, feat16 + i0);
    if (blockIdx.x < 16) {                       // 16 blocks * 2048 = 32768 W elems
        conv8(W + i0, Wb + i0);
    }
    if (blockIdx.x == 16 && threadIdx.x < 256) stats[threadIdx.x] = 0.0f;
}

// ---------------- G: gather + mean-agg -> h16 [Nr][256] bf16 (bf16 source) ----------------
// 64 nodes/block, 16-lane groups x 16B; 12-deep batched loads (2 batches + tail).
__global__ __launch_bounds__(256, 3) void k_gather16(
    const ushort_t* __restrict__ feat16,
    const int* __restrict__ self_idx,
    const int* __restrict__ neigh_idx,
    ushort_t* __restrict__ h16, int N)
{
    __shared__ int s_nidx[64 * S_NEIGH];
    __shared__ int s_sidx[64];
    const int t = threadIdx.x;
    const int base = blockIdx.x * 64;
    const int nvalid = min(64, N - base);
    const int V = nvalid * S_NEIGH;
    const long goff = (long)base * S_NEIGH;
    for (int i = t; i < (64 * S_NEIGH) / 4; i += 256) {
        const int e0 = 4 * i;
        if (e0 + 3 < V) {
            ((int4*)s_nidx)[i] = *(const int4*)(neigh_idx + goff + e0);
        } else {
            #pragma unroll
            for (int e = 0; e < 4; ++e)
                if (e0 + e < V) s_nidx[e0 + e] = neigh_idx[goff + e0 + e];
        }
    }
    if (t < 64 && t < nvalid) s_sidx[t] = self_idx[base + t];
    __syncthreads();

    const int g = t >> 4;          // 0..15
    const int l16 = t & 15;
    const int eoff = l16 * 8;      // element offset within a 128-elem row
    #pragma unroll
    for (int rep = 0; rep < 4; ++rep) {
        const int n = rep * 16 + g;
        if (n < nvalid) {
            const long gn = base + n;
            const uint4 sf = *(const uint4*)(feat16 + (long)s_sidx[n] * D + eoff);
            *(uint4*)(h16 + gn * TWO_D + eoff) = sf;          // self -> cols 0..127
            const int* nid = s_nidx + n * S_NEIGH;
            float ae[8] = {0.f,0.f,0.f,0.f,0.f,0.f,0.f,0.f};  // even-u chain
            float ao[8] = {0.f,0.f,0.f,0.f,0.f,0.f,0.f,0.f};  // odd-u chain
            #pragma unroll
            for (int b = 0; b < 2; ++b) {
                uint4 buf[12];                                // 12 loads in flight
                #pragma unroll
                for (int u = 0; u < 12; ++u)
                    buf[u] = *(const uint4*)(feat16 + (long)nid[b * 12 + u] * D + eoff);
                #pragma unroll
                for (int u = 0; u < 12; ++u) {
                    const uint_t* pu = (const uint_t*)&buf[u];
                    float* ac = (u & 1) ? ao : ae;
                    #pragma unroll
                    for (int j = 0; j < 4; ++j) {
                        const uint_t w = pu[j];
                        ac[2 * j]     += __uint_as_float(w << 16);
                        ac[2 * j + 1] += __uint_as_float(w & 0xFFFF0000u);
                    }
                }
            }
            {   // neighbor 24
                const uint4 f24 = *(const uint4*)(feat16 + (long)nid[24] * D + eoff);
                const uint_t* pu = (const uint_t*)&f24;
                #pragma unroll
                for (int j = 0; j < 4; ++j) {
                    const uint_t w = pu[j];
                    ae[2 * j]     += __uint_as_float(w << 16);
                    ae[2 * j + 1] += __uint_as_float(w & 0xFFFF0000u);
                }
            }
            const float r = 1.0f / S_NEIGH;
            uint_t o[4];
            #pragma unroll
            for (int j = 0; j < 4; ++j)
                o[j] = f2bf_bits((ae[2 * j] + ao[2 * j]) * r) |
                       (f2bf_bits((ae[2 * j + 1] + ao[2 * j + 1]) * r) << 16);
            *(uint4*)(h16 + gn * TWO_D + D + eoff) = *(uint4*)o;  // agg -> cols 128..255
        }
    }
}

// ---------------- G32: fallback gather from fp32 feat (no conv table) ----------------
__global__ __launch_bounds__(256, 4) void k_gather32(
    const float* __restrict__ feat,
    const int* __restrict__ self_idx,
    const int* __restrict__ neigh_idx,
    ushort_t* __restrict__ h16, int N)
{
    __shared__ int s_nidx[64 * S_NEIGH];
    __shared__ int s_sidx[64];
    const int t = threadIdx.x;
    const int base = blockIdx.x * 64;
    const int nvalid = min(64, N - base);
    const int V = nvalid * S_NEIGH;
    const long goff = (long)base * S_NEIGH;
    for (int i = t; i < (64 * S_NEIGH) / 4; i += 256) {
        const int e0 = 4 * i;
        if (e0 + 3 < V) {
            ((int4*)s_nidx)[i] = *(const int4*)(neigh_idx + goff + e0);
        } else {
            #pragma unroll
            for (int e = 0; e < 4; ++e)
                if (e0 + e < V) s_nidx[e0 + e] = neigh_idx[goff + e0 + e];
        }
    }
    if (t < 64 && t < nvalid) s_sidx[t] = self_idx[base + t];
    __syncthreads();

    const int g = t >> 5;
    const int l32 = t & 31;
    const int eoff = l32 * 4;
    #pragma unroll
    for (int rep = 0; rep < 8; ++rep) {
        const int n = rep * 8 + g;
        if (n < nvalid) {
            const long gn = base + n;
            const float4 sf = *(const float4*)(feat + (long)s_sidx[n] * D + eoff);
            uint_t so[2];
            so[0] = f2bf_bits(sf.x) | (f2bf_bits(sf.y) << 16);
            so[1] = f2bf_bits(sf.z) | (f2bf_bits(sf.w) << 16);
            *(uint2*)(h16 + gn * TWO_D + eoff) = *(uint2*)so;
            const int* nid = s_nidx + n * S_NEIGH;
            float a0 = 0.f, a1 = 0.f, a2 = 0.f, a3 = 0.f;
            #pragma unroll
            for (int b = 0; b < 5; ++b) {
                float4 buf[5];
                #pragma unroll
                for (int u = 0; u < 5; ++u)
                    buf[u] = *(const float4*)(feat + (long)nid[b * 5 + u] * D + eoff);
                #pragma unroll
                for (int u = 0; u < 5; ++u) {
                    a0 += buf[u].x; a1 += buf[u].y; a2 += buf[u].z; a3 += buf[u].w;
                }
            }
            const float r = 1.0f / S_NEIGH;
            uint_t o[2];
            o[0] = f2bf_bits(a0 * r) | (f2bf_bits(a1 * r) << 16);
            o[1] = f2bf_bits(a2 * r) | (f2bf_bits(a3 * r) << 16);
            *(uint2*)(h16 + gn * TWO_D + D + eoff) = *(uint2*)o;
        }
    }
}

// ---------------- M: MFMA GEMM out1b = relu(h16 @ Wb^T + b) [bf16] + column stats ----------------
// 512 thr = 8 waves; 128 nodes/block (16/wave); 128 cols = 8 n-tiles; K=256 = 8 k-steps.
// B (=W row-major) staged in LDS once per block, XOR-swizzled 16B granules.
__global__ __launch_bounds__(512, 2) void k_gemm(
    const ushort_t* __restrict__ h16,
    const ushort_t* __restrict__ Wb,
    const float* __restrict__ bias,
    ushort_t* __restrict__ out1b,   // [Nr][128] bf16 pre-norm output (ws)
    float* __restrict__ stats,
    int N)
{
    __shared__ ushort_t lds_b[32768];      // 64 KB
    __shared__ float lds_s[8][D];
    __shared__ float lds_q[8][D];

    const int t = threadIdx.x;
    // stage Wb -> LDS with granule swizzle: granule g of row r stored at g ^ (r&7)
    #pragma unroll
    for (int it = 0; it < 8; ++it) {
        const int i = it * 512 + t;        // 0..4095 granules (16B each)
        const int row = i >> 5;
        const int gr  = i & 31;
        const uint4 v = *(const uint4*)(Wb + row * TWO_D + gr * 8);
        *(uint4*)(lds_b + row * TWO_D + ((gr ^ (row & 7)) * 8)) = v;
    }
    __syncthreads();

    const int wv = t >> 6;                  // 0..7
    const int l  = t & 63;
    const int lm = l & 15;
    const int lh = l >> 4;                  // 0..3
    const int mb = blockIdx.x * 128 + wv * 16;

    // A fragments for this wave's 16 nodes, all K (8 k-steps) in regs
    short8 a[8];
    const long arow = (long)(mb + lm) * TWO_D;
    #pragma unroll
    for (int ks = 0; ks < 8; ++ks)
        a[ks] = *(const short8*)(h16 + arow + ks * 32 + lh * 8);

    f32x4 acc[8];
    #pragma unroll
    for (int nt = 0; nt < 8; ++nt) {
        const float bc = bias[nt * 16 + lm];
        acc[nt] = (f32x4){bc, bc, bc, bc};
    }

    #pragma unroll
    for (int nt = 0; nt < 8; ++nt) {
        const int colrow = nt * 16 + lm;    // storage row in lds_b = output column
        #pragma unroll
        for (int ks = 0; ks < 8; ++ks) {
            const short8 b = *(const short8*)(lds_b + colrow * TWO_D +
                                              (((ks * 4 + lh) ^ (l & 7)) * 8));
            acc[nt] = __builtin_amdgcn_mfma_f32_16x16x32_bf16(a[ks], b, acc[nt], 0, 0, 0);
        }
    }

    // epilogue: relu + bf16 store + column partial sums (C layout: col=lm, row=lh*4+r)
    #pragma unroll
    for (int nt = 0; nt < 8; ++nt) {
        float cs = 0.f, cq = 0.f;
        #pragma unroll
        for (int r = 0; r < 4; ++r) {
            const int node = mb + lh * 4 + r;
            const float v = fmaxf(acc[nt][r], 0.f);
            if (node < N) {
                out1b[(long)node * D + nt * 16 + lm] = (ushort_t)f2bf_bits(v);
                cs += v; cq += v * v;
            }
        }
        cs += __shfl_xor(cs, 16); cq += __shfl_xor(cq, 16);
        cs += __shfl_xor(cs, 32); cq += __shfl_xor(cq, 32);
        if (l < 16) { lds_s[wv][nt * 16 + l] = cs; lds_q[wv][nt * 16 + l] = cq; }
    }
    __syncthreads();
    if (t < D) {
        float s = 0.f;
        #pragma unroll
        for (int w = 0; w < 8; ++w) s += lds_s[w][t];
        atomicAdd(&stats[t], s);
    } else if (t < TWO_D) {
        const int j = t - D;
        float q = 0.f;
        #pragma unroll
        for (int w = 0; w < 8; ++w) q += lds_q[w][j];
        atomicAdd(&stats[D + j], q);
    }
}

// ---------------- F: batchnorm finalize + row L2 normalize (bf16 in, fp32 out) ----------------
__global__ __launch_bounds__(256) void k_final(
    const ushort_t* __restrict__ out1b,
    float* __restrict__ out,
    const float* __restrict__ stats,
    const float* __restrict__ gamma,
    const float* __restrict__ beta,
    int N)
{
    __shared__ float scale[D];
    __shared__ float shift[D];
    const int t = threadIdx.x;
    if (t < D) {
        const float invN = 1.0f / (float)N;
        const float mu = stats[t] * invN;
        const float var = stats[D + t] * invN - mu * mu;
        const float sc = gamma[t] * rsqrtf(var + BN_EPS_C);
        scale[t] = sc;
        shift[t] = beta[t] - mu * sc;
    }
    __syncthreads();

    const int row = blockIdx.x * 8 + (t >> 5);
    const int l = t & 31;
    if (row < N) {
        const uint2 xb = *(const uint2*)(out1b + (long)row * D + 4 * l);
        float x0 = __uint_as_float(xb.x << 16);
        float x1 = __uint_as_float(xb.x & 0xFFFF0000u);
        float x2 = __uint_as_float(xb.y << 16);
        float x3 = __uint_as_float(xb.y & 0xFFFF0000u);
        const float4 s4 = *(const float4*)&scale[4 * l];
        const float4 f4 = *(const float4*)&shift[4 * l];
        float4 y;
        y.x = x0 * s4.x + f4.x;
        y.y = x1 * s4.y + f4.y;
        y.z = x2 * s4.z + f4.z;
        y.w = x3 * s4.w + f4.w;
        float ss = y.x*y.x + y.y*y.y + y.z*y.z + y.w*y.w;
        #pragma unroll
        for (int m = 16; m >= 1; m >>= 1) ss += __shfl_xor(ss, m);
        const float inv = 1.0f / (sqrtf(ss) + NORM_EPS_C);
        y.x *= inv; y.y *= inv; y.z *= inv; y.w *= inv;
        *(float4*)(out + (long)row * D + 4 * l) = y;
    }
}

extern "C" void kernel_launch(void* const* d_in, const int* in_sizes, int n_in,
                              void* d_out, int out_size, void* d_ws, size_t ws_size,
                              hipStream_t stream) {
    const float* feat      = (const float*)d_in[0];
    const int*   self_idx  = (const int*)d_in[1];
    const int*   neigh_idx = (const int*)d_in[2];
    const float* W         = (const float*)d_in[3];
    const float* b         = (const float*)d_in[4];
    const float* gamma     = (const float*)d_in[5];
    const float* beta      = (const float*)d_in[6];
    float* out = (float*)d_out;
    const int N = in_sizes[1];                 // 50000
    const long n_total = in_sizes[0] / D;      // 200000
    const int gblk = (N + 63) / 64;            // gather blocks (782)
    const int mblk = (N + 127) / 128;          // gemm blocks (391)
    const long nr = (long)mblk * 128;          // 50048 rounded rows

    const size_t feat16_bytes = (size_t)n_total * D * 2;        // 51.2 MB
    const size_t h16_bytes    = (size_t)nr * TWO_D * 2;         // 25.6 MB
    const size_t o1_bytes     = (size_t)nr * D * 2;             // 12.8 MB
    const size_t wb_bytes     = (size_t)D * TWO_D * 2;          // 64 KB
    const size_t stats_bytes  = 256 * 4;
    const bool full = ws_size >= feat16_bytes + h16_bytes + o1_bytes + wb_bytes + stats_bytes;

    char* p = (char*)d_ws;
    ushort_t* feat16 = nullptr;
    if (full) { feat16 = (ushort_t*)p; p += feat16_bytes; }
    ushort_t* h16   = (ushort_t*)p; p += h16_bytes;
    ushort_t* out1b = (ushort_t*)p; p += o1_bytes;
    ushort_t* Wb    = (ushort_t*)p; p += wb_bytes;
    float* stats    = (float*)p;

    if (full) {
        k_conv<<<(int)(n_total * D / (256 * 8)), 256, 0, stream>>>(feat, feat16, W, Wb, stats);
        k_gather16<<<gblk, 256, 0, stream>>>(feat16, self_idx, neigh_idx, h16, N);
    } else {
        k_conv<<<16, 256, 0, stream>>>(W, Wb, W, Wb, stats);   // blocks 0..15 convert W only
        hipMemsetAsync(stats, 0, 256 * 4, stream);
        k_gather32<<<gblk, 256, 0, stream>>>(feat, self_idx, neigh_idx, h16, N);
    }
    k_gemm<<<mblk, 512, 0, stream>>>(h16, Wb, b, out1b, stats, N);
    k_final<<<(N + 7) / 8, 256, 0, stream>>>(out1b, out, stats, gamma, beta, N);
}

// Round 8
// 103.845 us; speedup vs baseline: 1.8283x; 1.0019x over previous
//
#include <hip/hip_runtime.h>
#include <hip/hip_cooperative_groups.h>
#include <math.h>

namespace cg = cooperative_groups;

typedef __attribute__((ext_vector_type(8))) short short8;
typedef __attribute__((ext_vector_type(4))) float f32x4;
typedef unsigned short ushort_t;
typedef unsigned int uint_t;

#define D 128
#define TWO_D 256
#define S_NEIGH 25

static constexpr float BN_EPS_C = 1e-5f;
static constexpr float NORM_EPS_C = 1e-6f;

__device__ __forceinline__ uint_t f2bf_bits(float f) {
    // round-to-nearest-even bf16 (inputs are finite)
    uint_t u = __float_as_uint(f);
    return (u + 0x7FFFu + ((u >> 16) & 1u)) >> 16;
}

__device__ __forceinline__ void conv8(const float* __restrict__ src, ushort_t* __restrict__ dst) {
    const float4 f0 = *(const float4*)(src);
    const float4 f1 = *(const float4*)(src + 4);
    uint_t o[4];
    o[0] = f2bf_bits(f0.x) | (f2bf_bits(f0.y) << 16);
    o[1] = f2bf_bits(f0.z) | (f2bf_bits(f0.w) << 16);
    o[2] = f2bf_bits(f1.x) | (f2bf_bits(f1.y) << 16);
    o[3] = f2bf_bits(f1.z) | (f2bf_bits(f1.w) << 16);
    *(uint4*)(dst) = *(uint4*)o;
}

// ---------------- P: feat fp32 -> bf16 table; W -> bf16; zero stats (fused) ----------------
__global__ __launch_bounds__(256) void k_conv(const float* __restrict__ feat,
                                              ushort_t* __restrict__ feat16,
                                              const float* __restrict__ W,
                                              ushort_t* __restrict__ Wb,
                                              float* __restrict__ stats) {
    const long i0 = ((long)blockIdx.x * 256 + threadIdx.x) * 8;
    conv8(feat + i0, feat16 + i0);
    if (blockIdx.x < 16) {                       // 16 blocks * 2048 = 32768 W elems
        conv8(W + i0, Wb + i0);
    }
    if (blockIdx.x == 16 && threadIdx.x < 256) stats[threadIdx.x] = 0.0f;
}

// ---------------- G: gather + mean-agg -> h16 [Nr][256] bf16 (bf16 source) ----------------
// 64 nodes/block, 16-lane groups x 16B; 12-deep batched loads (2 batches + tail).
__global__ __launch_bounds__(256, 3) void k_gather16(
    const ushort_t* __restrict__ feat16,
    const int* __restrict__ self_idx,
    const int* __restrict__ neigh_idx,
    ushort_t* __restrict__ h16, int N)
{
    __shared__ int s_nidx[64 * S_NEIGH];
    __shared__ int s_sidx[64];
    const int t = threadIdx.x;
    const int base = blockIdx.x * 64;
    const int nvalid = min(64, N - base);
    const int V = nvalid * S_NEIGH;
    const long goff = (long)base * S_NEIGH;
    for (int i = t; i < (64 * S_NEIGH) / 4; i += 256) {
        const int e0 = 4 * i;
        if (e0 + 3 < V) {
            ((int4*)s_nidx)[i] = *(const int4*)(neigh_idx + goff + e0);
        } else {
            #pragma unroll
            for (int e = 0; e < 4; ++e)
                if (e0 + e < V) s_nidx[e0 + e] = neigh_idx[goff + e0 + e];
        }
    }
    if (t < 64 && t < nvalid) s_sidx[t] = self_idx[base + t];
    __syncthreads();

    const int g = t >> 4;          // 0..15
    const int l16 = t & 15;
    const int eoff = l16 * 8;      // element offset within a 128-elem row
    #pragma unroll
    for (int rep = 0; rep < 4; ++rep) {
        const int n = rep * 16 + g;
        if (n < nvalid) {
            const long gn = base + n;
            const uint4 sf = *(const uint4*)(feat16 + (long)s_sidx[n] * D + eoff);
            *(uint4*)(h16 + gn * TWO_D + eoff) = sf;          // self -> cols 0..127
            const int* nid = s_nidx + n * S_NEIGH;
            float ae[8] = {0.f,0.f,0.f,0.f,0.f,0.f,0.f,0.f};  // even-u chain
            float ao[8] = {0.f,0.f,0.f,0.f,0.f,0.f,0.f,0.f};  // odd-u chain
            #pragma unroll
            for (int b = 0; b < 2; ++b) {
                uint4 buf[12];                                // 12 loads in flight
                #pragma unroll
                for (int u = 0; u < 12; ++u)
                    buf[u] = *(const uint4*)(feat16 + (long)nid[b * 12 + u] * D + eoff);
                #pragma unroll
                for (int u = 0; u < 12; ++u) {
                    const uint_t* pu = (const uint_t*)&buf[u];
                    float* ac = (u & 1) ? ao : ae;
                    #pragma unroll
                    for (int j = 0; j < 4; ++j) {
                        const uint_t w = pu[j];
                        ac[2 * j]     += __uint_as_float(w << 16);
                        ac[2 * j + 1] += __uint_as_float(w & 0xFFFF0000u);
                    }
                }
            }
            {   // neighbor 24
                const uint4 f24 = *(const uint4*)(feat16 + (long)nid[24] * D + eoff);
                const uint_t* pu = (const uint_t*)&f24;
                #pragma unroll
                for (int j = 0; j < 4; ++j) {
                    const uint_t w = pu[j];
                    ae[2 * j]     += __uint_as_float(w << 16);
                    ae[2 * j + 1] += __uint_as_float(w & 0xFFFF0000u);
                }
            }
            const float r = 1.0f / S_NEIGH;
            uint_t o[4];
            #pragma unroll
            for (int j = 0; j < 4; ++j)
                o[j] = f2bf_bits((ae[2 * j] + ao[2 * j]) * r) |
                       (f2bf_bits((ae[2 * j + 1] + ao[2 * j + 1]) * r) << 16);
            *(uint4*)(h16 + gn * TWO_D + D + eoff) = *(uint4*)o;  // agg -> cols 128..255
        }
    }
}

// ---------------- G32: fallback gather from fp32 feat (no conv table) ----------------
__global__ __launch_bounds__(256, 4) void k_gather32(
    const float* __restrict__ feat,
    const int* __restrict__ self_idx,
    const int* __restrict__ neigh_idx,
    ushort_t* __restrict__ h16, int N)
{
    __shared__ int s_nidx[64 * S_NEIGH];
    __shared__ int s_sidx[64];
    const int t = threadIdx.x;
    const int base = blockIdx.x * 64;
    const int nvalid = min(64, N - base);
    const int V = nvalid * S_NEIGH;
    const long goff = (long)base * S_NEIGH;
    for (int i = t; i < (64 * S_NEIGH) / 4; i += 256) {
        const int e0 = 4 * i;
        if (e0 + 3 < V) {
            ((int4*)s_nidx)[i] = *(const int4*)(neigh_idx + goff + e0);
        } else {
            #pragma unroll
            for (int e = 0; e < 4; ++e)
                if (e0 + e < V) s_nidx[e0 + e] = neigh_idx[goff + e0 + e];
        }
    }
    if (t < 64 && t < nvalid) s_sidx[t] = self_idx[base + t];
    __syncthreads();

    const int g = t >> 5;
    const int l32 = t & 31;
    const int eoff = l32 * 4;
    #pragma unroll
    for (int rep = 0; rep < 8; ++rep) {
        const int n = rep * 8 + g;
        if (n < nvalid) {
            const long gn = base + n;
            const float4 sf = *(const float4*)(feat + (long)s_sidx[n] * D + eoff);
            uint_t so[2];
            so[0] = f2bf_bits(sf.x) | (f2bf_bits(sf.y) << 16);
            so[1] = f2bf_bits(sf.z) | (f2bf_bits(sf.w) << 16);
            *(uint2*)(h16 + gn * TWO_D + eoff) = *(uint2*)so;
            const int* nid = s_nidx + n * S_NEIGH;
            float a0 = 0.f, a1 = 0.f, a2 = 0.f, a3 = 0.f;
            #pragma unroll
            for (int b = 0; b < 5; ++b) {
                float4 buf[5];
                #pragma unroll
                for (int u = 0; u < 5; ++u)
                    buf[u] = *(const float4*)(feat + (long)nid[b * 5 + u] * D + eoff);
                #pragma unroll
                for (int u = 0; u < 5; ++u) {
                    a0 += buf[u].x; a1 += buf[u].y; a2 += buf[u].z; a3 += buf[u].w;
                }
            }
            const float r = 1.0f / S_NEIGH;
            uint_t o[2];
            o[0] = f2bf_bits(a0 * r) | (f2bf_bits(a1 * r) << 16);
            o[1] = f2bf_bits(a2 * r) | (f2bf_bits(a3 * r) << 16);
            *(uint2*)(h16 + gn * TWO_D + D + eoff) = *(uint2*)o;
        }
    }
}

// ---------------- MF: cooperative fused MFMA GEMM + BN + L2-norm -> d_out ----------------
// 512 thr = 8 waves; 128 nodes/block; stats atomics -> grid.sync -> epilogue from registers.
__global__ __launch_bounds__(512, 4) void k_gemm_fused(
    const ushort_t* __restrict__ h16,
    const ushort_t* __restrict__ Wb,
    const float* __restrict__ bias,
    const float* __restrict__ gamma,
    const float* __restrict__ beta,
    float* __restrict__ out,        // [N][128] fp32 final output
    float* __restrict__ stats,
    int N)
{
    __shared__ ushort_t lds_b[32768];      // 64 KB
    __shared__ float lds_s[8][D];
    __shared__ float lds_q[8][D];

    const int t = threadIdx.x;
    // stage Wb -> LDS with granule swizzle: granule g of row r stored at g ^ (r&7)
    #pragma unroll
    for (int it = 0; it < 8; ++it) {
        const int i = it * 512 + t;        // 0..4095 granules (16B each)
        const int row = i >> 5;
        const int gr  = i & 31;
        const uint4 v = *(const uint4*)(Wb + row * TWO_D + gr * 8);
        *(uint4*)(lds_b + row * TWO_D + ((gr ^ (row & 7)) * 8)) = v;
    }
    __syncthreads();

    const int wv = t >> 6;                  // 0..7
    const int l  = t & 63;
    const int lm = l & 15;
    const int lh = l >> 4;                  // 0..3
    const int mb = blockIdx.x * 128 + wv * 16;

    short8 a[8];
    const long arow = (long)(mb + lm) * TWO_D;
    #pragma unroll
    for (int ks = 0; ks < 8; ++ks)
        a[ks] = *(const short8*)(h16 + arow + ks * 32 + lh * 8);

    f32x4 acc[8];
    #pragma unroll
    for (int nt = 0; nt < 8; ++nt) {
        const float bc = bias[nt * 16 + lm];
        acc[nt] = (f32x4){bc, bc, bc, bc};
    }

    #pragma unroll
    for (int nt = 0; nt < 8; ++nt) {
        const int colrow = nt * 16 + lm;    // storage row in lds_b = output column
        #pragma unroll
        for (int ks = 0; ks < 8; ++ks) {
            const short8 b = *(const short8*)(lds_b + colrow * TWO_D +
                                              (((ks * 4 + lh) ^ (l & 7)) * 8));
            acc[nt] = __builtin_amdgcn_mfma_f32_16x16x32_bf16(a[ks], b, acc[nt], 0, 0, 0);
        }
    }

    // relu in place + column partial sums (C layout: col=nt*16+lm, row=mb+lh*4+r)
    #pragma unroll
    for (int nt = 0; nt < 8; ++nt) {
        float cs = 0.f, cq = 0.f;
        #pragma unroll
        for (int r = 0; r < 4; ++r) {
            const float v = fmaxf(acc[nt][r], 0.f);
            acc[nt][r] = v;
            if (mb + lh * 4 + r < N) { cs += v; cq += v * v; }
        }
        cs += __shfl_xor(cs, 16); cq += __shfl_xor(cq, 16);
        cs += __shfl_xor(cs, 32); cq += __shfl_xor(cq, 32);
        if (l < 16) { lds_s[wv][nt * 16 + l] = cs; lds_q[wv][nt * 16 + l] = cq; }
    }
    __syncthreads();
    if (t < D) {
        float s = 0.f;
        #pragma unroll
        for (int w = 0; w < 8; ++w) s += lds_s[w][t];
        atomicAdd(&stats[t], s);
    } else if (t < TWO_D) {
        const int j = t - D;
        float q = 0.f;
        #pragma unroll
        for (int w = 0; w < 8; ++w) q += lds_q[w][j];
        atomicAdd(&stats[D + j], q);
    }

    cg::this_grid().sync();

    // BN scale/shift from global stats (reuse lds_s/lds_q row 0)
    float* scale = &lds_s[0][0];
    float* shift = &lds_q[0][0];
    if (t < D) {
        const float invN = 1.0f / (float)N;
        const float mu = stats[t] * invN;
        const float var = stats[D + t] * invN - mu * mu;
        const float sc = gamma[t] * rsqrtf(var + BN_EPS_C);
        scale[t] = sc;
        shift[t] = beta[t] - mu * sc;
    }
    __syncthreads();

    float sc8[8], sh8[8];
    #pragma unroll
    for (int nt = 0; nt < 8; ++nt) {
        sc8[nt] = scale[nt * 16 + lm];
        sh8[nt] = shift[nt * 16 + lm];
    }

    // per-node BN + row L2 norm from registers; write fp32 out
    #pragma unroll
    for (int r = 0; r < 4; ++r) {
        float ss = 0.f;
        #pragma unroll
        for (int nt = 0; nt < 8; ++nt) {
            const float y = acc[nt][r] * sc8[nt] + sh8[nt];
            ss += y * y;
        }
        ss += __shfl_xor(ss, 1); ss += __shfl_xor(ss, 2);
        ss += __shfl_xor(ss, 4); ss += __shfl_xor(ss, 8);
        const float inv = 1.0f / (sqrtf(ss) + NORM_EPS_C);
        const int node = mb + lh * 4 + r;
        if (node < N) {
            #pragma unroll
            for (int nt = 0; nt < 8; ++nt) {
                const float y = acc[nt][r] * sc8[nt] + sh8[nt];
                out[(long)node * D + nt * 16 + lm] = y * inv;
            }
        }
    }
}

// ---------------- M: non-cooperative GEMM (fallback) ----------------
__global__ __launch_bounds__(512, 2) void k_gemm(
    const ushort_t* __restrict__ h16,
    const ushort_t* __restrict__ Wb,
    const float* __restrict__ bias,
    ushort_t* __restrict__ out1b,   // [Nr][128] bf16 pre-norm output (ws)
    float* __restrict__ stats,
    int N)
{
    __shared__ ushort_t lds_b[32768];
    __shared__ float lds_s[8][D];
    __shared__ float lds_q[8][D];

    const int t = threadIdx.x;
    #pragma unroll
    for (int it = 0; it < 8; ++it) {
        const int i = it * 512 + t;
        const int row = i >> 5;
        const int gr  = i & 31;
        const uint4 v = *(const uint4*)(Wb + row * TWO_D + gr * 8);
        *(uint4*)(lds_b + row * TWO_D + ((gr ^ (row & 7)) * 8)) = v;
    }
    __syncthreads();

    const int wv = t >> 6;
    const int l  = t & 63;
    const int lm = l & 15;
    const int lh = l >> 4;
    const int mb = blockIdx.x * 128 + wv * 16;

    short8 a[8];
    const long arow = (long)(mb + lm) * TWO_D;
    #pragma unroll
    for (int ks = 0; ks < 8; ++ks)
        a[ks] = *(const short8*)(h16 + arow + ks * 32 + lh * 8);

    f32x4 acc[8];
    #pragma unroll
    for (int nt = 0; nt < 8; ++nt) {
        const float bc = bias[nt * 16 + lm];
        acc[nt] = (f32x4){bc, bc, bc, bc};
    }

    #pragma unroll
    for (int nt = 0; nt < 8; ++nt) {
        const int colrow = nt * 16 + lm;
        #pragma unroll
        for (int ks = 0; ks < 8; ++ks) {
            const short8 b = *(const short8*)(lds_b + colrow * TWO_D +
                                              (((ks * 4 + lh) ^ (l & 7)) * 8));
            acc[nt] = __builtin_amdgcn_mfma_f32_16x16x32_bf16(a[ks], b, acc[nt], 0, 0, 0);
        }
    }

    #pragma unroll
    for (int nt = 0; nt < 8; ++nt) {
        float cs = 0.f, cq = 0.f;
        #pragma unroll
        for (int r = 0; r < 4; ++r) {
            const int node = mb + lh * 4 + r;
            const float v = fmaxf(acc[nt][r], 0.f);
            if (node < N) {
                out1b[(long)node * D + nt * 16 + lm] = (ushort_t)f2bf_bits(v);
                cs += v; cq += v * v;
            }
        }
        cs += __shfl_xor(cs, 16); cq += __shfl_xor(cq, 16);
        cs += __shfl_xor(cs, 32); cq += __shfl_xor(cq, 32);
        if (l < 16) { lds_s[wv][nt * 16 + l] = cs; lds_q[wv][nt * 16 + l] = cq; }
    }
    __syncthreads();
    if (t < D) {
        float s = 0.f;
        #pragma unroll
        for (int w = 0; w < 8; ++w) s += lds_s[w][t];
        atomicAdd(&stats[t], s);
    } else if (t < TWO_D) {
        const int j = t - D;
        float q = 0.f;
        #pragma unroll
        for (int w = 0; w < 8; ++w) q += lds_q[w][j];
        atomicAdd(&stats[D + j], q);
    }
}

// ---------------- F: batchnorm finalize + row L2 normalize (fallback) ----------------
__global__ __launch_bounds__(256) void k_final(
    const ushort_t* __restrict__ out1b,
    float* __restrict__ out,
    const float* __restrict__ stats,
    const float* __restrict__ gamma,
    const float* __restrict__ beta,
    int N)
{
    __shared__ float scale[D];
    __shared__ float shift[D];
    const int t = threadIdx.x;
    if (t < D) {
        const float invN = 1.0f / (float)N;
        const float mu = stats[t] * invN;
        const float var = stats[D + t] * invN - mu * mu;
        const float sc = gamma[t] * rsqrtf(var + BN_EPS_C);
        scale[t] = sc;
        shift[t] = beta[t] - mu * sc;
    }
    __syncthreads();

    const int row = blockIdx.x * 8 + (t >> 5);
    const int l = t & 31;
    if (row < N) {
        const uint2 xb = *(const uint2*)(out1b + (long)row * D + 4 * l);
        float x0 = __uint_as_float(xb.x << 16);
        float x1 = __uint_as_float(xb.x & 0xFFFF0000u);
        float x2 = __uint_as_float(xb.y << 16);
        float x3 = __uint_as_float(xb.y & 0xFFFF0000u);
        const float4 s4 = *(const float4*)&scale[4 * l];
        const float4 f4 = *(const float4*)&shift[4 * l];
        float4 y;
        y.x = x0 * s4.x + f4.x;
        y.y = x1 * s4.y + f4.y;
        y.z = x2 * s4.z + f4.z;
        y.w = x3 * s4.w + f4.w;
        float ss = y.x*y.x + y.y*y.y + y.z*y.z + y.w*y.w;
        #pragma unroll
        for (int m = 16; m >= 1; m >>= 1) ss += __shfl_xor(ss, m);
        const float inv = 1.0f / (sqrtf(ss) + NORM_EPS_C);
        y.x *= inv; y.y *= inv; y.z *= inv; y.w *= inv;
        *(float4*)(out + (long)row * D + 4 * l) = y;
    }
}

extern "C" void kernel_launch(void* const* d_in, const int* in_sizes, int n_in,
                              void* d_out, int out_size, void* d_ws, size_t ws_size,
                              hipStream_t stream) {
    const float* feat      = (const float*)d_in[0];
    const int*   self_idx  = (const int*)d_in[1];
    const int*   neigh_idx = (const int*)d_in[2];
    const float* W         = (const float*)d_in[3];
    const float* b         = (const float*)d_in[4];
    const float* gamma     = (const float*)d_in[5];
    const float* beta      = (const float*)d_in[6];
    float* out = (float*)d_out;
    const int N = in_sizes[1];                 // 50000
    const long n_total = in_sizes[0] / D;      // 200000
    const int gblk = (N + 63) / 64;            // gather blocks (782)
    const int mblk = (N + 127) / 128;          // gemm blocks (391)
    const long nr = (long)mblk * 128;          // 50048 rounded rows

    const size_t feat16_bytes = (size_t)n_total * D * 2;        // 51.2 MB
    const size_t h16_bytes    = (size_t)nr * TWO_D * 2;         // 25.6 MB
    const size_t o1_bytes     = (size_t)nr * D * 2;             // 12.8 MB (fallback only)
    const size_t wb_bytes     = (size_t)D * TWO_D * 2;          // 64 KB
    const size_t stats_bytes  = 256 * 4;
    const bool full = ws_size >= feat16_bytes + h16_bytes + o1_bytes + wb_bytes + stats_bytes;

    char* p = (char*)d_ws;
    ushort_t* feat16 = nullptr;
    if (full) { feat16 = (ushort_t*)p; p += feat16_bytes; }
    ushort_t* h16   = (ushort_t*)p; p += h16_bytes;
    ushort_t* out1b = (ushort_t*)p; p += o1_bytes;
    ushort_t* Wb    = (ushort_t*)p; p += wb_bytes;
    float* stats    = (float*)p;

    if (full) {
        k_conv<<<(int)(n_total * D / (256 * 8)), 256, 0, stream>>>(feat, feat16, W, Wb, stats);
        k_gather16<<<gblk, 256, 0, stream>>>(feat16, self_idx, neigh_idx, h16, N);
    } else {
        k_conv<<<16, 256, 0, stream>>>(W, Wb, W, Wb, stats);   // blocks 0..15 convert W only
        hipMemsetAsync(stats, 0, 256 * 4, stream);
        k_gather32<<<gblk, 256, 0, stream>>>(feat, self_idx, neigh_idx, h16, N);
    }

    // cooperative fused tail if co-residency allows; else proven 2-kernel tail
    int dev = 0;
    hipGetDevice(&dev);
    int coopAttr = 0, nCU = 0, maxB = 0;
    hipDeviceGetAttribute(&coopAttr, hipDeviceAttributeCooperativeLaunch, dev);
    hipDeviceGetAttribute(&nCU, hipDeviceAttributeMultiprocessorCount, dev);
    hipOccupancyMaxActiveBlocksPerMultiprocessor(&maxB, k_gemm_fused, 512, 0);
    const bool coop = coopAttr && ((long)maxB * nCU >= mblk);

    if (coop) {
        void* args[] = {(void*)&h16, (void*)&Wb, (void*)&b, (void*)&gamma,
                        (void*)&beta, (void*)&out, (void*)&stats, (void*)&N};
        hipLaunchCooperativeKernel((void*)k_gemm_fused, dim3(mblk), dim3(512),
                                   args, 0, stream);
    } else {
        k_gemm<<<mblk, 512, 0, stream>>>(h16, Wb, b, out1b, stats, N);
        k_final<<<(N + 7) / 8, 256, 0, stream>>>(out1b, out, stats, gamma, beta, N);
    }
}

// Round 9
// 95.698 us; speedup vs baseline: 1.9839x; 1.0851x over previous
//
#include <hip/hip_runtime.h>
#include <math.h>

typedef __attribute__((ext_vector_type(8))) short short8;
typedef __attribute__((ext_vector_type(4))) float f32x4;
typedef unsigned short ushort_t;
typedef unsigned int uint_t;

#define D 128
#define TWO_D 256
#define S_NEIGH 25

static constexpr float BN_EPS_C = 1e-5f;
static constexpr float NORM_EPS_C = 1e-6f;

__device__ __forceinline__ uint_t f2bf_bits(float f) {
    // round-to-nearest-even bf16 (inputs are finite)
    uint_t u = __float_as_uint(f);
    return (u + 0x7FFFu + ((u >> 16) & 1u)) >> 16;
}

__device__ __forceinline__ void conv8(const float* __restrict__ src, ushort_t* __restrict__ dst) {
    const float4 f0 = *(const float4*)(src);
    const float4 f1 = *(const float4*)(src + 4);
    uint_t o[4];
    o[0] = f2bf_bits(f0.x) | (f2bf_bits(f0.y) << 16);
    o[1] = f2bf_bits(f0.z) | (f2bf_bits(f0.w) << 16);
    o[2] = f2bf_bits(f1.x) | (f2bf_bits(f1.y) << 16);
    o[3] = f2bf_bits(f1.z) | (f2bf_bits(f1.w) << 16);
    *(uint4*)(dst) = *(uint4*)o;
}

// ---------------- P: feat fp32 -> bf16 table; W -> bf16; zero stats (fused) ----------------
__global__ __launch_bounds__(256) void k_conv(const float* __restrict__ feat,
                                              ushort_t* __restrict__ feat16,
                                              const float* __restrict__ W,
                                              ushort_t* __restrict__ Wb,
                                              float* __restrict__ stats) {
    const long i0 = ((long)blockIdx.x * 256 + threadIdx.x) * 8;
    conv8(feat + i0, feat16 + i0);
    if (blockIdx.x < 16) {                       // 16 blocks * 2048 = 32768 W elems
        conv8(W + i0, Wb + i0);
    }
    if (blockIdx.x == 16 && threadIdx.x < 256) stats[threadIdx.x] = 0.0f;
}

// ---------------- FG: fused gather + MFMA GEMM ----------------
// 512 thr = 8 waves; 64 nodes/block. Gather -> LDS h (bf16, XOR-swizzled 16B granules),
// W in registers (each wave owns 16 output cols), MFMA from LDS, relu+stats+bf16 out.
__global__ __launch_bounds__(512, 4) void k_fused(
    const ushort_t* __restrict__ feat16,
    const int* __restrict__ self_idx,
    const int* __restrict__ neigh_idx,
    const ushort_t* __restrict__ Wb,
    const float* __restrict__ bias,
    ushort_t* __restrict__ out1b,   // [N][128] bf16 pre-norm output (ws)
    float* __restrict__ stats,
    int N)
{
    __shared__ int s_nidx[64 * S_NEIGH];     // 6400 B
    __shared__ int s_sidx[64];
    __shared__ ushort_t h_lds[64 * TWO_D];   // 32 KB, swizzled granules

    const int t = threadIdx.x;
    const int base = blockIdx.x * 64;
    const int nvalid = min(64, N - base);

    // ---- stage indices (one coalesced sweep) ----
    {
        const int V = nvalid * S_NEIGH;
        const long goff = (long)base * S_NEIGH;
        if (t < (64 * S_NEIGH) / 4) {            // 400 int4 loaders
            const int e0 = 4 * t;
            if (e0 + 3 < V) {
                ((int4*)s_nidx)[t] = *(const int4*)(neigh_idx + goff + e0);
            } else {
                #pragma unroll
                for (int e = 0; e < 4; ++e)
                    if (e0 + e < V) s_nidx[e0 + e] = neigh_idx[goff + e0 + e];
            }
        } else if (t >= 448) {
            const int i = t - 448;
            if (i < nvalid) s_sidx[i] = self_idx[base + i];
        }
    }
    __syncthreads();

    // ---- gather into LDS: 32 groups of 16 lanes, 2 nodes each; 12-deep batched loads ----
    {
        const int g = t >> 4;          // 0..31
        const int l16 = t & 15;
        const int eoff = l16 * 8;      // element offset within a 128-elem row
        #pragma unroll
        for (int rep = 0; rep < 2; ++rep) {
            const int n = rep * 32 + g;
            ushort_t* hrow = h_lds + n * TWO_D;
            const int gs = (l16 ^ (n & 7)) * 8;            // self granule (swizzled)
            const int ga = ((16 + l16) ^ (n & 7)) * 8;     // agg granule  (swizzled)
            if (n < nvalid) {
                const uint4 sf = *(const uint4*)(feat16 + (long)s_sidx[n] * D + eoff);
                *(uint4*)(hrow + gs) = sf;
                const int* nid = s_nidx + n * S_NEIGH;
                float ae[8] = {0.f,0.f,0.f,0.f,0.f,0.f,0.f,0.f};
                float ao[8] = {0.f,0.f,0.f,0.f,0.f,0.f,0.f,0.f};
                #pragma unroll
                for (int b = 0; b < 2; ++b) {
                    uint4 buf[12];
                    #pragma unroll
                    for (int u = 0; u < 12; ++u)
                        buf[u] = *(const uint4*)(feat16 + (long)nid[b * 12 + u] * D + eoff);
                    #pragma unroll
                    for (int u = 0; u < 12; ++u) {
                        const uint_t* pu = (const uint_t*)&buf[u];
                        float* ac = (u & 1) ? ao : ae;
                        #pragma unroll
                        for (int j = 0; j < 4; ++j) {
                            const uint_t w = pu[j];
                            ac[2 * j]     += __uint_as_float(w << 16);
                            ac[2 * j + 1] += __uint_as_float(w & 0xFFFF0000u);
                        }
                    }
                }
                {   // neighbor 24
                    const uint4 f24 = *(const uint4*)(feat16 + (long)nid[24] * D + eoff);
                    const uint_t* pu = (const uint_t*)&f24;
                    #pragma unroll
                    for (int j = 0; j < 4; ++j) {
                        const uint_t w = pu[j];
                        ae[2 * j]     += __uint_as_float(w << 16);
                        ae[2 * j + 1] += __uint_as_float(w & 0xFFFF0000u);
                    }
                }
                const float r = 1.0f / S_NEIGH;
                uint_t o[4];
                #pragma unroll
                for (int j = 0; j < 4; ++j)
                    o[j] = f2bf_bits((ae[2 * j] + ao[2 * j]) * r) |
                           (f2bf_bits((ae[2 * j + 1] + ao[2 * j + 1]) * r) << 16);
                *(uint4*)(hrow + ga) = *(uint4*)o;
            } else {
                const uint4 z = make_uint4(0, 0, 0, 0);
                *(uint4*)(hrow + gs) = z;
                *(uint4*)(hrow + ga) = z;
            }
        }
    }
    __syncthreads();

    // ---- GEMM: wave wv owns output cols [16wv,16wv+16); W fragment in registers ----
    const int wv = t >> 6;                  // 0..7
    const int l  = t & 63;
    const int lm = l & 15;
    const int lh = l >> 4;                  // 0..3
    const int colg = 16 * wv + lm;          // this lane's output column

    short8 b_reg[8];
    #pragma unroll
    for (int ks = 0; ks < 8; ++ks)
        b_reg[ks] = *(const short8*)(Wb + (long)colg * TWO_D + ks * 32 + lh * 8);

    const float bc = bias[colg];
    f32x4 acc[4];
    #pragma unroll
    for (int mt = 0; mt < 4; ++mt) acc[mt] = (f32x4){bc, bc, bc, bc};

    #pragma unroll
    for (int mt = 0; mt < 4; ++mt) {
        const int arow = mt * 16 + lm;      // node row within block
        #pragma unroll
        for (int ks = 0; ks < 8; ++ks) {
            const short8 a = *(const short8*)(h_lds + arow * TWO_D +
                                              (((ks * 4 + lh) ^ (lm & 7)) * 8));
            acc[mt] = __builtin_amdgcn_mfma_f32_16x16x32_bf16(a, b_reg[ks], acc[mt], 0, 0, 0);
        }
    }

    // ---- epilogue: relu + bf16 store + column sums (C layout: col=lm, row=lh*4+r) ----
    float cs = 0.f, cq = 0.f;
    #pragma unroll
    for (int mt = 0; mt < 4; ++mt) {
        #pragma unroll
        for (int r = 0; r < 4; ++r) {
            const int node = base + mt * 16 + lh * 4 + r;
            const float v = fmaxf(acc[mt][r], 0.f);
            if (node < N) {
                out1b[(long)node * D + colg] = (ushort_t)f2bf_bits(v);
                cs += v; cq += v * v;
            }
        }
    }
    cs += __shfl_xor(cs, 16); cq += __shfl_xor(cq, 16);
    cs += __shfl_xor(cs, 32); cq += __shfl_xor(cq, 32);
    if (l < 16) {                            // one owner wave per column
        atomicAdd(&stats[16 * wv + l], cs);
        atomicAdd(&stats[D + 16 * wv + l], cq);
    }
}

// ---------------- G32: fallback gather from fp32 feat (no conv table) ----------------
__global__ __launch_bounds__(256, 4) void k_gather32(
    const float* __restrict__ feat,
    const int* __restrict__ self_idx,
    const int* __restrict__ neigh_idx,
    ushort_t* __restrict__ h16, int N)
{
    __shared__ int s_nidx[64 * S_NEIGH];
    __shared__ int s_sidx[64];
    const int t = threadIdx.x;
    const int base = blockIdx.x * 64;
    const int nvalid = min(64, N - base);
    const int V = nvalid * S_NEIGH;
    const long goff = (long)base * S_NEIGH;
    for (int i = t; i < (64 * S_NEIGH) / 4; i += 256) {
        const int e0 = 4 * i;
        if (e0 + 3 < V) {
            ((int4*)s_nidx)[i] = *(const int4*)(neigh_idx + goff + e0);
        } else {
            #pragma unroll
            for (int e = 0; e < 4; ++e)
                if (e0 + e < V) s_nidx[e0 + e] = neigh_idx[goff + e0 + e];
        }
    }
    if (t < 64 && t < nvalid) s_sidx[t] = self_idx[base + t];
    __syncthreads();

    const int g = t >> 5;
    const int l32 = t & 31;
    const int eoff = l32 * 4;
    #pragma unroll
    for (int rep = 0; rep < 8; ++rep) {
        const int n = rep * 8 + g;
        if (n < nvalid) {
            const long gn = base + n;
            const float4 sf = *(const float4*)(feat + (long)s_sidx[n] * D + eoff);
            uint_t so[2];
            so[0] = f2bf_bits(sf.x) | (f2bf_bits(sf.y) << 16);
            so[1] = f2bf_bits(sf.z) | (f2bf_bits(sf.w) << 16);
            *(uint2*)(h16 + gn * TWO_D + eoff) = *(uint2*)so;
            const int* nid = s_nidx + n * S_NEIGH;
            float a0 = 0.f, a1 = 0.f, a2 = 0.f, a3 = 0.f;
            #pragma unroll
            for (int b = 0; b < 5; ++b) {
                float4 buf[5];
                #pragma unroll
                for (int u = 0; u < 5; ++u)
                    buf[u] = *(const float4*)(feat + (long)nid[b * 5 + u] * D + eoff);
                #pragma unroll
                for (int u = 0; u < 5; ++u) {
                    a0 += buf[u].x; a1 += buf[u].y; a2 += buf[u].z; a3 += buf[u].w;
                }
            }
            const float r = 1.0f / S_NEIGH;
            uint_t o[2];
            o[0] = f2bf_bits(a0 * r) | (f2bf_bits(a1 * r) << 16);
            o[1] = f2bf_bits(a2 * r) | (f2bf_bits(a3 * r) << 16);
            *(uint2*)(h16 + gn * TWO_D + D + eoff) = *(uint2*)o;
        }
    }
}

// ---------------- M: non-fused GEMM (fallback path) ----------------
__global__ __launch_bounds__(512, 2) void k_gemm(
    const ushort_t* __restrict__ h16,
    const ushort_t* __restrict__ Wb,
    const float* __restrict__ bias,
    ushort_t* __restrict__ out1b,
    float* __restrict__ stats,
    int N)
{
    __shared__ ushort_t lds_b[32768];
    __shared__ float lds_s[8][D];
    __shared__ float lds_q[8][D];

    const int t = threadIdx.x;
    #pragma unroll
    for (int it = 0; it < 8; ++it) {
        const int i = it * 512 + t;
        const int row = i >> 5;
        const int gr  = i & 31;
        const uint4 v = *(const uint4*)(Wb + row * TWO_D + gr * 8);
        *(uint4*)(lds_b + row * TWO_D + ((gr ^ (row & 7)) * 8)) = v;
    }
    __syncthreads();

    const int wv = t >> 6;
    const int l  = t & 63;
    const int lm = l & 15;
    const int lh = l >> 4;
    const int mb = blockIdx.x * 128 + wv * 16;

    short8 a[8];
    const long arow = (long)(mb + lm) * TWO_D;
    #pragma unroll
    for (int ks = 0; ks < 8; ++ks)
        a[ks] = *(const short8*)(h16 + arow + ks * 32 + lh * 8);

    f32x4 acc[8];
    #pragma unroll
    for (int nt = 0; nt < 8; ++nt) {
        const float bc = bias[nt * 16 + lm];
        acc[nt] = (f32x4){bc, bc, bc, bc};
    }

    #pragma unroll
    for (int nt = 0; nt < 8; ++nt) {
        const int colrow = nt * 16 + lm;
        #pragma unroll
        for (int ks = 0; ks < 8; ++ks) {
            const short8 b = *(const short8*)(lds_b + colrow * TWO_D +
                                              (((ks * 4 + lh) ^ (l & 7)) * 8));
            acc[nt] = __builtin_amdgcn_mfma_f32_16x16x32_bf16(a[ks], b, acc[nt], 0, 0, 0);
        }
    }

    #pragma unroll
    for (int nt = 0; nt < 8; ++nt) {
        float cs = 0.f, cq = 0.f;
        #pragma unroll
        for (int r = 0; r < 4; ++r) {
            const int node = mb + lh * 4 + r;
            const float v = fmaxf(acc[nt][r], 0.f);
            if (node < N) {
                out1b[(long)node * D + nt * 16 + lm] = (ushort_t)f2bf_bits(v);
                cs += v; cq += v * v;
            }
        }
        cs += __shfl_xor(cs, 16); cq += __shfl_xor(cq, 16);
        cs += __shfl_xor(cs, 32); cq += __shfl_xor(cq, 32);
        if (l < 16) { lds_s[wv][nt * 16 + l] = cs; lds_q[wv][nt * 16 + l] = cq; }
    }
    __syncthreads();
    if (t < D) {
        float s = 0.f;
        #pragma unroll
        for (int w = 0; w < 8; ++w) s += lds_s[w][t];
        atomicAdd(&stats[t], s);
    } else if (t < TWO_D) {
        const int j = t - D;
        float q = 0.f;
        #pragma unroll
        for (int w = 0; w < 8; ++w) q += lds_q[w][j];
        atomicAdd(&stats[D + j], q);
    }
}

// ---------------- F: batchnorm finalize + row L2 normalize (bf16 in, fp32 out) ----------------
__global__ __launch_bounds__(256) void k_final(
    const ushort_t* __restrict__ out1b,
    float* __restrict__ out,
    const float* __restrict__ stats,
    const float* __restrict__ gamma,
    const float* __restrict__ beta,
    int N)
{
    __shared__ float scale[D];
    __shared__ float shift[D];
    const int t = threadIdx.x;
    if (t < D) {
        const float invN = 1.0f / (float)N;
        const float mu = stats[t] * invN;
        const float var = stats[D + t] * invN - mu * mu;
        const float sc = gamma[t] * rsqrtf(var + BN_EPS_C);
        scale[t] = sc;
        shift[t] = beta[t] - mu * sc;
    }
    __syncthreads();

    const int row = blockIdx.x * 8 + (t >> 5);
    const int l = t & 31;
    if (row < N) {
        const uint2 xb = *(const uint2*)(out1b + (long)row * D + 4 * l);
        float x0 = __uint_as_float(xb.x << 16);
        float x1 = __uint_as_float(xb.x & 0xFFFF0000u);
        float x2 = __uint_as_float(xb.y << 16);
        float x3 = __uint_as_float(xb.y & 0xFFFF0000u);
        const float4 s4 = *(const float4*)&scale[4 * l];
        const float4 f4 = *(const float4*)&shift[4 * l];
        float4 y;
        y.x = x0 * s4.x + f4.x;
        y.y = x1 * s4.y + f4.y;
        y.z = x2 * s4.z + f4.z;
        y.w = x3 * s4.w + f4.w;
        float ss = y.x*y.x + y.y*y.y + y.z*y.z + y.w*y.w;
        #pragma unroll
        for (int m = 16; m >= 1; m >>= 1) ss += __shfl_xor(ss, m);
        const float inv = 1.0f / (sqrtf(ss) + NORM_EPS_C);
        y.x *= inv; y.y *= inv; y.z *= inv; y.w *= inv;
        *(float4*)(out + (long)row * D + 4 * l) = y;
    }
}

extern "C" void kernel_launch(void* const* d_in, const int* in_sizes, int n_in,
                              void* d_out, int out_size, void* d_ws, size_t ws_size,
                              hipStream_t stream) {
    const float* feat      = (const float*)d_in[0];
    const int*   self_idx  = (const int*)d_in[1];
    const int*   neigh_idx = (const int*)d_in[2];
    const float* W         = (const float*)d_in[3];
    const float* b         = (const float*)d_in[4];
    const float* gamma     = (const float*)d_in[5];
    const float* beta      = (const float*)d_in[6];
    float* out = (float*)d_out;
    const int N = in_sizes[1];                 // 50000
    const long n_total = in_sizes[0] / D;      // 200000
    const int gblk = (N + 63) / 64;            // 64-node blocks (782)
    const int mblk = (N + 127) / 128;          // fallback gemm blocks (391)
    const long nr = (long)mblk * 128;          // 50048 rounded rows

    const size_t feat16_bytes = (size_t)n_total * D * 2;        // 51.2 MB
    const size_t h16_bytes    = (size_t)nr * TWO_D * 2;         // 25.6 MB (fallback only)
    const size_t o1_bytes     = (size_t)nr * D * 2;             // 12.8 MB
    const size_t wb_bytes     = (size_t)D * TWO_D * 2;          // 64 KB
    const size_t stats_bytes  = 256 * 4;
    const bool full = ws_size >= feat16_bytes + h16_bytes + o1_bytes + wb_bytes + stats_bytes;

    char* p = (char*)d_ws;
    ushort_t* feat16 = nullptr;
    if (full) { feat16 = (ushort_t*)p; p += feat16_bytes; }
    ushort_t* h16   = (ushort_t*)p; p += h16_bytes;
    ushort_t* out1b = (ushort_t*)p; p += o1_bytes;
    ushort_t* Wb    = (ushort_t*)p; p += wb_bytes;
    float* stats    = (float*)p;

    if (full) {
        k_conv<<<(int)(n_total * D / (256 * 8)), 256, 0, stream>>>(feat, feat16, W, Wb, stats);
        k_fused<<<gblk, 512, 0, stream>>>(feat16, self_idx, neigh_idx, Wb, b, out1b, stats, N);
    } else {
        k_conv<<<16, 256, 0, stream>>>(W, Wb, W, Wb, stats);   // blocks 0..15 convert W only
        hipMemsetAsync(stats, 0, 256 * 4, stream);
        k_gather32<<<gblk, 256, 0, stream>>>(feat, self_idx, neigh_idx, h16, N);
        k_gemm<<<mblk, 512, 0, stream>>>(h16, Wb, b, out1b, stats, N);
    }
    k_final<<<(N + 7) / 8, 256, 0, stream>>>(out1b, out, stats, gamma, beta, N);
}